// Round 5
// baseline (20885.676 us; speedup 1.0000x reference)
//
#include <hip/hip_runtime.h>
#include <hip/hip_bf16.h>

// ---------------------------------------------------------------------------
// BiLSTM (persistent bf16-MFMA kernel, register-resident weights + cell state,
// BARRIER-FREE data-flow sync: consumers poll sentinel-initialized h slots;
// producers fire-and-forget stores) + CRF forward.
// This revision: HALVE the all-gather degree. 128 blocks x 512 threads
// (8 waves); each block owns 32 h-columns; a group = 16 blocks on ONE XCD
// (bid&7 round-robin, runtime-VERIFIED via HW_REG_XCC_ID). vs round-4
// (256x256, degree 32): half the skew (max-of-16), half the poll L2 traffic,
// per-thread poll = 2 chunks (per-lane incremental via exec mask), 2
// waves/SIMD. Keeps round-4's proven schedule: sentinel/sc0 data-fused poll,
// VGPR-staged x prefetch, LDS-only raw barriers (no vmcnt drain), h store
// right after elementwise with expcnt(0) hazard fix.
constexpr int B_ = 64, S_ = 512, E_ = 300, H_ = 512, T_ = 12;
constexpr int G4 = 4 * H_;          // 2048 gate rows
constexpr int KPADX = 320;          // E padded to 320 (zeros 300..319)
constexpr int KTOT = KPADX + H_;    // 832 total K (x | h)
constexpr int KC_TOT = KTOT / 32;   // 26 MFMA k-chunks
constexpr int KC_X = KPADX / 32;    // 10 x-only chunks (h-independent)
constexpr int NT16 = G4 / 16;       // 128 16-wide n tiles
constexpr float NEGV = -10000.0f;
constexpr int ASTR = 840;           // LDS A-row stride in shorts (832 + 8)
constexpr unsigned SENT = 0xFFFFFFFFu;  // sentinel dword (bf16 pair = -NaN,-NaN)

typedef __attribute__((ext_vector_type(8))) short bf16x8_t;
typedef __attribute__((ext_vector_type(4))) float f32x4_t;
typedef __attribute__((ext_vector_type(4))) unsigned u32x4_t;

// ---- workspace layout (bytes) ---------------------------------------------
constexpr size_t WC_OFF = 0;
constexpr size_t WC_BYTES = (size_t)2 * NT16 * KC_TOT * 64 * 8 * 2;  // 6,815,744
constexpr size_t XC_OFF = WC_OFF + WC_BYTES;
constexpr size_t XC_BYTES = (size_t)S_ * B_ * KPADX * 2;             // 20,971,520
constexpr size_t HH_OFF = XC_OFF + XC_BYTES;
constexpr size_t HH_BYTES = (size_t)2 * (S_ + 1) * B_ * H_ * 2;      // 67,239,936
constexpr size_t FE_OFF = HH_OFF + HH_BYTES;
constexpr size_t FE_BYTES = (size_t)S_ * B_ * T_ * 4;                // 1,572,864
constexpr size_t LSE_OFF = FE_OFF + FE_BYTES;
// CHK: 128 u32 placement-check slots INSIDE the FE region (feats_kernel runs
// after lstm_persist and fully rewrites FE, so this costs no workspace).
constexpr size_t CHK_OFF = FE_OFF;
constexpr int NBLK = 128;           // lstm blocks (16 per group x 8 groups)

// raw barrier: order LDS only; leave global loads in flight (no vmcnt drain).
#define BAR_LDS() do {                                         \
    asm volatile("s_waitcnt lgkmcnt(0)" ::: "memory");         \
    __builtin_amdgcn_s_barrier();                              \
    __builtin_amdgcn_sched_barrier(0);                         \
  } while (0)

// ---------------------------------------------------------------------------
// prep: (1) weights -> bf16 MFMA B-fragment order; (2) h0 -> bf16 h_hist slot
// 0; (3) embedding gather xc[s][b][320] bf16; (4) sentinel-fill hh slots 1..S;
// (5) sentinel-fill the 128-entry XCC placement-check array (in FE region).
__global__ void prep_kernel(const float* __restrict__ Wih_f, const float* __restrict__ Whh_f,
                            const float* __restrict__ Wih_b, const float* __restrict__ Whh_b,
                            const float* __restrict__ h0,
                            const int* __restrict__ tokens, const float* __restrict__ Wemb,
                            char* __restrict__ ws) {
  __hip_bfloat16* wc = (__hip_bfloat16*)(ws + WC_OFF);
  __hip_bfloat16* xc = (__hip_bfloat16*)(ws + XC_OFF);
  __hip_bfloat16* hh = (__hip_bfloat16*)(ws + HH_OFF);
  const int WCN = 2 * NT16 * KC_TOT * 64;   // 425,984
  const int H0N = 2 * B_ * H_;              // 65,536
  const int XCN = S_ * B_ * (KPADX / 8);    // 1,310,720
  const int SFD = (S_ * B_ * H_ * 2) / 16;  // 2,097,152 uint4 per dir
  int idx = blockIdx.x * 256 + threadIdx.x;
  if (idx < WCN) {
    int lane = idx & 63;
    int r = idx >> 6;
    int kc = r % KC_TOT; r /= KC_TOT;
    int tt = r % NT16;
    int dir = r / NT16;
    int n16 = lane & 15, quad = lane >> 4;
    int nt = tt >> 2, gate = tt & 3;
    int j = gate * H_ + nt * 16 + n16;   // original gate row
    int k0 = kc * 32 + quad * 8;
    const float* Wih = dir ? Wih_b : Wih_f;
    const float* Whh = dir ? Whh_b : Whh_f;
    __hip_bfloat16* dst = wc + (size_t)idx * 8;
    #pragma unroll
    for (int jj = 0; jj < 8; jj++) {
      int k = k0 + jj;
      float f;
      if (k < E_) f = Wih[(size_t)j * E_ + k];
      else if (k < KPADX) f = 0.f;
      else f = Whh[(size_t)j * H_ + (k - KPADX)];
      dst[jj] = __float2bfloat16(f);
    }
  } else if (idx < WCN + H0N) {
    int i = idx - WCN;                       // dir*B*H + b*H + h
    int dir = i / (B_ * H_), rem = i % (B_ * H_);
    hh[(size_t)dir * (S_ + 1) * B_ * H_ + rem] = __float2bfloat16(h0[i]);
  } else if (idx < WCN + H0N + XCN) {
    int i = idx - WCN - H0N;                 // sb*40 + c8
    int c8 = i % 40, sb = i / 40;            // sb = s*B + b
    int s = sb >> 6, b = sb & 63;
    int k0 = c8 * 8;
    const float* src = Wemb + (size_t)tokens[(size_t)b * S_ + s] * E_;
    __hip_bfloat16 v[8];
    if (k0 + 8 <= E_) {
      float4 f0 = *(const float4*)(src + k0);
      float4 f1 = *(const float4*)(src + k0 + 4);
      v[0] = __float2bfloat16(f0.x); v[1] = __float2bfloat16(f0.y);
      v[2] = __float2bfloat16(f0.z); v[3] = __float2bfloat16(f0.w);
      v[4] = __float2bfloat16(f1.x); v[5] = __float2bfloat16(f1.y);
      v[6] = __float2bfloat16(f1.z); v[7] = __float2bfloat16(f1.w);
    } else {
      #pragma unroll
      for (int jj = 0; jj < 8; jj++) {
        int k = k0 + jj;
        v[jj] = __float2bfloat16(k < E_ ? src[k] : 0.f);
      }
    }
    *(uint4*)(xc + (size_t)sb * KPADX + k0) = *(const uint4*)v;
  } else if (idx < WCN + H0N + XCN + 2 * SFD) {
    int i = idx - WCN - H0N - XCN;
    int dir = i / SFD, j = i % SFD;
    // sentinel-fill hh[dir][1..S][*][*]
    uint4* dst = (uint4*)(hh + (size_t)dir * (S_ + 1) * B_ * H_ + B_ * H_);
    uint4 sv; sv.x = SENT; sv.y = SENT; sv.z = SENT; sv.w = SENT;
    dst[j] = sv;
  } else if (idx < WCN + H0N + XCN + 2 * SFD + NBLK) {
    ((unsigned*)(ws + CHK_OFF))[idx - (WCN + H0N + XCN + 2 * SFD)] = SENT;
  }
}

// ---------------------------------------------------------------------------
// Persistent BiLSTM. grid = 128 = group(8 = dir x mt, == bid&7 -> XCD) x
// member m(16 = bid>>3). block = 512 (8 waves; wave wv = (ntl=wv>>2,
// gate=wv&3) -> output h-cols m*32 + ntl*16 + l16). Weights in registers;
// cell state in a register. Consumers poll h(s) 16B chunks (2 per thread,
// sentinel-initialized, sc0 = XCD-local L2); producers fire-and-forget sc0
// dword stores.
__launch_bounds__(512, 1)
__global__ void lstm_persist(const float* __restrict__ bias_f,
                             const float* __restrict__ bias_b,
                             const float* __restrict__ c0,
                             char* __restrict__ ws) {
  __shared__ short pool[16 * ASTR];      // 26,880 B A-tile
  __shared__ float gl[4 * 16 * 34];      // 8,704 B gate exchange
  const int bid = blockIdx.x;
  // --- XCD-local remap: group g = bid&7 (round-robin -> one XCD per group) ---
  const int g = bid & 7, m = bid >> 3, dir = g >> 2, mt = g & 3;
  const int tid = threadIdx.x, lane = tid & 63, wv = tid >> 6;   // wv in [0,8)
  const int quad = lane >> 4, l16 = lane & 15;
  const int wgate = wv & 3, wntl = wv >> 2;   // this wave's gate / 16-col tile
  const __hip_bfloat16* wc = (const __hip_bfloat16*)(ws + WC_OFF);
  const __hip_bfloat16* xc = (const __hip_bfloat16*)(ws + XC_OFF);
  const __hip_bfloat16* hhb = (const __hip_bfloat16*)(ws + HH_OFF);
  unsigned* hh_u = (unsigned*)(ws + HH_OFF);

  // --- load B fragments into registers, once (tt = m*8 + wv in [0,128)) ---
  bf16x8_t bfr[KC_TOT];
  #pragma unroll
  for (int kc = 0; kc < KC_TOT; kc++) {
    size_t boff = (((size_t)dir * NT16 + (m * 8 + wv)) * KC_TOT + kc) * 64 + lane;
    bfr[kc] = *(const bf16x8_t*)(wc + boff * 8);
  }
  // --- per-thread cell state; per-wave bias (folded into gl at exchange) ---
  const int bo = tid >> 5, hl = tid & 31;       // batch-offset, h-offset(32)
  const int b = mt * 16 + bo, hg = m * 32 + hl;
  float c = c0[(size_t)(dir * B_ + b) * H_ + hg];
  const int whcol = m * 32 + wntl * 16 + l16;   // this lane's output column
  const float bias_w = (dir ? bias_b : bias_f)[wgate * H_ + whcol];

  // --- placement check: publish XCC id, poll all 128, decide uniformly ------
  int fastu;
  {
    unsigned* chk = (unsigned*)(ws + CHK_OFF);
    unsigned* chkl = (unsigned*)pool;          // reuse LDS as scratch
    if (tid == 0) {
      unsigned xcc;
      asm volatile("s_getreg_b32 %0, hwreg(HW_REG_XCC_ID)" : "=s"(xcc));
      __hip_atomic_store(chk + bid, xcc & 0xFu, __ATOMIC_RELAXED,
                         __HIP_MEMORY_SCOPE_AGENT);
    }
    if (tid < NBLK) {
      unsigned myv;
      for (;;) {
        myv = __hip_atomic_load(chk + tid, __ATOMIC_RELAXED,
                                __HIP_MEMORY_SCOPE_AGENT);
        if (myv != SENT) break;
        __builtin_amdgcn_s_sleep(4);
      }
      chkl[tid] = myv;
    }
    __syncthreads();
    bool f = true;
    unsigned mask = 0;
    for (int gg = 0; gg < 8; gg++) {
      unsigned v0 = chkl[gg];
      f = f && (v0 < 32u);
      mask |= (1u << (v0 & 31u));
      for (int mm = 1; mm < 16; mm++) f = f && (chkl[gg + 8 * mm] == v0);
    }
    f = f && (__popc(mask) == 8);   // 8 groups on 8 DISTINCT XCDs (garbage guard)
    fastu = __builtin_amdgcn_readfirstlane(f ? 1 : 0);
    __syncthreads();                // before pool reuse below
  }

  // --- pre-stage x(0) into pool x-region (640 16B chunks) ---
  {
    int spos0 = dir ? (S_ - 1) : 0;
    for (int i = tid; i < 16 * 40; i += 512) {
      int row = i / 40, c8 = i % 40;
      *(uint4*)(pool + row * ASTR + c8 * 8) =
          *(const uint4*)(xc + ((size_t)spos0 * B_ + mt * 16 + row) * KPADX + c8 * 8);
    }
  }
  __syncthreads();   // x(0) visible before first x-MFMA phase

  // poll/stage map: 16KB h tile = 1024 16B chunks; thread owns chunks tid and
  // tid+512: row = i>>6 (batch-offset), col16 = i&63.
  for (int s = 0; s < S_; s++) {
    // --- 1. x-part MFMAs (h-independent) ---
    f32x4_t acc = (f32x4_t)(0.f);
    #pragma unroll
    for (int kc = 0; kc < KC_X; kc++) {
      bf16x8_t af = *(const bf16x8_t*)(pool + l16 * ASTR + kc * 32 + quad * 8);
      acc = __builtin_amdgcn_mfma_f32_16x16x32_bf16(af, bfr[kc], acc, 0, 0, 0);
    }
    // --- 2. poll h(s): data-fused sentinel poll, 2 chunks/thread (sc0) ---
    const u32x4_t* pbase = (const u32x4_t*)(hhb +
        ((size_t)(dir * (S_ + 1) + s) * B_ + mt * 16) * H_);
    u32x4_t h0v, h1v;
    if (fastu) {
      const u32x4_t* q0 = pbase + tid;
      const u32x4_t* q1 = pbase + tid + 512;
      int tries = 0;
      for (;;) {
        asm volatile(
            "global_load_dwordx4 %0, %2, off sc0\n\t"
            "global_load_dwordx4 %1, %3, off sc0\n\t"
            "s_waitcnt vmcnt(0)"
            : "=&v"(h0v), "=&v"(h1v)
            : "v"(q0), "v"(q1)
            : "memory");
        bool ok = h0v[0] != SENT && h0v[1] != SENT && h0v[2] != SENT && h0v[3] != SENT &&
                  h1v[0] != SENT && h1v[1] != SENT && h1v[2] != SENT && h1v[3] != SENT;
        if (ok) break;
        // watchdog insurance: after ~2048 rounds also try the agent view
        if (++tries > 2048) {
          const unsigned long long* qq = (const unsigned long long*)pbase;
          unsigned long long a0 = __hip_atomic_load(qq + 2 * tid, __ATOMIC_RELAXED,
                                                    __HIP_MEMORY_SCOPE_AGENT);
          unsigned long long a1 = __hip_atomic_load(qq + 2 * tid + 1, __ATOMIC_RELAXED,
                                                    __HIP_MEMORY_SCOPE_AGENT);
          unsigned long long b0 = __hip_atomic_load(qq + 2 * (tid + 512), __ATOMIC_RELAXED,
                                                    __HIP_MEMORY_SCOPE_AGENT);
          unsigned long long b1 = __hip_atomic_load(qq + 2 * (tid + 512) + 1, __ATOMIC_RELAXED,
                                                    __HIP_MEMORY_SCOPE_AGENT);
          bool ok2 = (unsigned)a0 != SENT && (unsigned)(a0 >> 32) != SENT &&
                     (unsigned)a1 != SENT && (unsigned)(a1 >> 32) != SENT &&
                     (unsigned)b0 != SENT && (unsigned)(b0 >> 32) != SENT &&
                     (unsigned)b1 != SENT && (unsigned)(b1 >> 32) != SENT;
          if (ok2) {
            h0v[0] = (unsigned)a0; h0v[1] = (unsigned)(a0 >> 32);
            h0v[2] = (unsigned)a1; h0v[3] = (unsigned)(a1 >> 32);
            h1v[0] = (unsigned)b0; h1v[1] = (unsigned)(b0 >> 32);
            h1v[2] = (unsigned)b1; h1v[3] = (unsigned)(b1 >> 32);
            break;
          }
        }
        __builtin_amdgcn_s_sleep(1);
      }
    } else {
      // fallback: agent-scope sentinel poll (device-coherent, always safe)
      const unsigned long long* qq = (const unsigned long long*)pbase;
      bool ok = false;
      while (!ok) {
        unsigned long long a0 = __hip_atomic_load(qq + 2 * tid, __ATOMIC_RELAXED,
                                                  __HIP_MEMORY_SCOPE_AGENT);
        unsigned long long a1 = __hip_atomic_load(qq + 2 * tid + 1, __ATOMIC_RELAXED,
                                                  __HIP_MEMORY_SCOPE_AGENT);
        unsigned long long b0 = __hip_atomic_load(qq + 2 * (tid + 512), __ATOMIC_RELAXED,
                                                  __HIP_MEMORY_SCOPE_AGENT);
        unsigned long long b1 = __hip_atomic_load(qq + 2 * (tid + 512) + 1, __ATOMIC_RELAXED,
                                                  __HIP_MEMORY_SCOPE_AGENT);
        ok = (unsigned)a0 != SENT && (unsigned)(a0 >> 32) != SENT &&
             (unsigned)a1 != SENT && (unsigned)(a1 >> 32) != SENT &&
             (unsigned)b0 != SENT && (unsigned)(b0 >> 32) != SENT &&
             (unsigned)b1 != SENT && (unsigned)(b1 >> 32) != SENT;
        if (ok) {
          h0v[0] = (unsigned)a0; h0v[1] = (unsigned)(a0 >> 32);
          h0v[2] = (unsigned)a1; h0v[3] = (unsigned)(a1 >> 32);
          h1v[0] = (unsigned)b0; h1v[1] = (unsigned)(b0 >> 32);
          h1v[2] = (unsigned)b1; h1v[3] = (unsigned)(b1 >> 32);
        } else {
          __builtin_amdgcn_s_sleep(1);
        }
      }
    }
    // --- 3. stage h(s) -> LDS h-region (before xpf issue so h0v/h1v regs
    //        die and can be reused for xpf by the allocator) ---
    {
      int r0 = tid >> 6, c0v = tid & 63;
      *(u32x4_t*)(pool + r0 * ASTR + KPADX + c0v * 8) = h0v;
      int i1 = tid + 512; int r1 = i1 >> 6, c1v = i1 & 63;
      *(u32x4_t*)(pool + r1 * ASTR + KPADX + c1v * 8) = h1v;
    }
    // --- 4. issue x(s+1) prefetch loads into VGPRs (consumed at step 9) ---
    u32x4_t xpf0, xpf1;
    const bool xok = (s + 1 < S_);
    if (xok) {
      int sposn = dir ? (S_ - 2 - s) : (s + 1);
      const u32x4_t* xq = (const u32x4_t*)xc;   // 8 bf16 per u32x4
      xpf0 = xq[((size_t)sposn * B_ + mt * 16 + tid / 40) * 40 + tid % 40];
      if (tid < 128) {
        int i1 = tid + 512;
        xpf1 = xq[((size_t)sposn * B_ + mt * 16 + i1 / 40) * 40 + i1 % 40];
      }
    }
    BAR_LDS();   // B1: h tile staged (LDS-only wait; xpf loads stay in flight)
    // --- 5. h-part MFMAs (same accumulation order: kc 10..25) ---
    #pragma unroll
    for (int kc = KC_X; kc < KC_TOT; kc++) {
      bf16x8_t af = *(const bf16x8_t*)(pool + l16 * ASTR + kc * 32 + quad * 8);
      acc = __builtin_amdgcn_mfma_f32_16x16x32_bf16(af, bfr[kc], acc, 0, 0, 0);
    }
    // --- 6. gate exchange (+bias): C/D row = quad*4+r (batch), col = l16 ---
    #pragma unroll
    for (int r = 0; r < 4; r++)
      gl[(wgate * 16 + quad * 4 + r) * 34 + wntl * 16 + l16] = acc[r] + bias_w;
    BAR_LDS();   // B2: gl ready + all pool A-reads complete
    // --- 7. elementwise cell update (c in register; biases already in gl) ---
    float gi = gl[(0 * 16 + bo) * 34 + hl];
    float gf = gl[(1 * 16 + bo) * 34 + hl];
    float gg = gl[(2 * 16 + bo) * 34 + hl];
    float go = gl[(3 * 16 + bo) * 34 + hl];
    float ii = 1.f / (1.f + __expf(-gi));
    float ff = 1.f / (1.f + __expf(-gf));
    float gt = 1.f - 2.f / (1.f + __expf(2.f * gg));   // tanh
    float oo = 1.f / (1.f + __expf(-go));
    c = ff * c + ii * gt;
    float hv2 = oo * (1.f - 2.f / (1.f + __expf(2.f * c)));
    // --- 8. h store: pack 2 bf16 -> one sc0 dword store; fire-and-forget ---
    float hn = __shfl_xor(hv2, 1, 64);    // partner shares (bo, hl^1)
    if ((hl & 1) == 0) {
      unsigned short ulo = __builtin_bit_cast(unsigned short, __float2bfloat16(hv2));
      unsigned short uhi = __builtin_bit_cast(unsigned short, __float2bfloat16(hn));
      unsigned pk = ((unsigned)uhi << 16) | (unsigned)ulo;
      size_t uidx = (((size_t)(dir * (S_ + 1) + s + 1) * B_ + b) * H_ + hg) >> 1;
      if (fastu) {
        // expcnt(0) inside the asm: VMEM stores read their data VGPR
        // asynchronously; without it the compiler may reuse pk's register
        // before the store consumes it (round-0 hang mechanism).
        asm volatile("global_store_dword %0, %1, off sc0\n\t"
                     "s_waitcnt expcnt(0)"
                     :: "v"(hh_u + uidx), "v"(pk) : "memory");
      } else {
        __hip_atomic_store(hh_u + uidx, pk, __ATOMIC_RELAXED,
                           __HIP_MEMORY_SCOPE_AGENT);
      }
    }
    // --- 9. write prefetched x(s+1) into pool x-region (loads long landed) ---
    if (xok) {
      *(u32x4_t*)(pool + (tid / 40) * ASTR + (tid % 40) * 8) = xpf0;
      if (tid < 128) {
        int i1 = tid + 512;
        *(u32x4_t*)(pool + (i1 / 40) * ASTR + (i1 % 40) * 8) = xpf1;
      }
    }
    BAR_LDS();   // B3: x(s+1) staged for next iteration's x-MFMAs
  }
}

// ---------------------------------------------------------------------------
// feats[(b*S+s)*T + t] = [hf(s) | hb(s)] . W_out[t,:] + b_out[t]. block per s.
// Output layout [b][s][t] so the CRF scan reads contiguously per batch.
// LDS tile stride padded 1024->1032 to break the 4-way t-lane bank conflict.
__launch_bounds__(256)
__global__ void feats_kernel(const float* __restrict__ Wout,
                             const float* __restrict__ bout,
                             char* __restrict__ ws) {
  __shared__ float wl[12 * 1032];   // 49,536 B
  const int s = blockIdx.x, tid = threadIdx.x;
  for (int i = tid; i < 12 * 1024 / 4; i += 256) {
    int idx4 = i * 4;
    int t = idx4 >> 10, k = idx4 & 1023;
    *(float4*)(wl + t * 1032 + k) = *(const float4*)(Wout + idx4);
  }
  __syncthreads();
  const __hip_bfloat16* hh = (const __hip_bfloat16*)(ws + HH_OFF);
  float* fe = (float*)(ws + FE_OFF);
  int b = tid >> 2, tg = tid & 3, t0 = tg * 3;
  const __hip_bfloat16* hf = hh + (size_t)(0 * (S_ + 1) + s + 1) * B_ * H_ + (size_t)b * H_;
  const __hip_bfloat16* hb = hh + (size_t)(1 * (S_ + 1) + (S_ - s)) * B_ * H_ + (size_t)b * H_;
  float a0 = 0.f, a1 = 0.f, a2 = 0.f;
  for (int half = 0; half < 2; half++) {
    const __hip_bfloat16* hp = half ? hb : hf;
    int wof = half * 512;
    for (int k = 0; k < 512; k += 8) {
      uint4 raw = *(const uint4*)(hp + k);
      const __hip_bfloat16* hv = (const __hip_bfloat16*)&raw;
      float hfl[8];
      #pragma unroll
      for (int j = 0; j < 8; j++) hfl[j] = __bfloat162float(hv[j]);
      #pragma unroll
      for (int j = 0; j < 8; j++) {
        a0 += hfl[j] * wl[(t0 + 0) * 1032 + wof + k + j];
        a1 += hfl[j] * wl[(t0 + 1) * 1032 + wof + k + j];
        a2 += hfl[j] * wl[(t0 + 2) * 1032 + wof + k + j];
      }
    }
  }
  float* o = fe + ((size_t)b * S_ + s) * T_;
  o[t0 + 0] = a0 + bout[t0 + 0];
  o[t0 + 1] = a1 + bout[t0 + 1];
  o[t0 + 2] = a2 + bout[t0 + 2];
}

// ---------------------------------------------------------------------------
// CRF forward scan: one wave per batch element; lane = next-tag (<12).
// Software-pipelined: load feat(s+1) while computing step s.
__launch_bounds__(64)
__global__ void crf_kernel(const int* __restrict__ lengths,
                           const float* __restrict__ trans,
                           char* __restrict__ ws) {
  const int b = blockIdx.x, lane = threadIdx.x;
  const float* fe = (const float*)(ws + FE_OFF);
  float* lse = (float*)(ws + LSE_OFF);
  const float* fb = fe + (size_t)b * S_ * T_;
  float tr[12];
  #pragma unroll
  for (int p = 0; p < 12; p++) tr[p] = (lane < 12) ? trans[lane * 12 + p] : 0.f;
  float tstop = (lane < 12) ? trans[11 * 12 + lane] : 0.f;  // STOP row
  float alpha = (lane == 10) ? 0.f : NEGV;                  // START tag
  const int len = lengths[b];
  float feat = (lane < 12) ? fb[lane] : 0.f;
  for (int s = 0; s < S_; s++) {
    float fn = (lane < 12 && s + 1 < S_) ? fb[(size_t)(s + 1) * T_ + lane] : 0.f;
    float av[12];
    #pragma unroll
    for (int p = 0; p < 12; p++) av[p] = __shfl(alpha, p, 64) + tr[p];
    float mx = av[0];
    #pragma unroll
    for (int p = 1; p < 12; p++) mx = fmaxf(mx, av[p]);
    float sum = 0.f;
    #pragma unroll
    for (int p = 0; p < 12; p++) sum += __expf(av[p] - mx);
    float nw = mx + __logf(sum) + feat;
    if (s < len && lane < 12) alpha = nw;
    feat = fn;
  }
  float tv = (lane < 12) ? (alpha + tstop) : -3.0e38f;
  float mx = tv;
  #pragma unroll
  for (int off = 32; off > 0; off >>= 1) mx = fmaxf(mx, __shfl_xor(mx, off, 64));
  float sum = __expf(tv - mx);
  #pragma unroll
  for (int off = 32; off > 0; off >>= 1) sum += __shfl_xor(sum, off, 64);
  if (lane == 0) lse[b] = mx + __logf(sum);
}

__global__ void final_kernel(char* __restrict__ ws, float* __restrict__ out) {
  const float* lse = (const float*)(ws + LSE_OFF);
  float v = lse[threadIdx.x];
  #pragma unroll
  for (int off = 32; off > 0; off >>= 1) v += __shfl_xor(v, off, 64);
  if (threadIdx.x == 0) out[0] = v * (1.f / 64.f);
}

// ---------------------------------------------------------------------------
extern "C" void kernel_launch(void* const* d_in, const int* in_sizes, int n_in,
                              void* d_out, int out_size, void* d_ws, size_t ws_size,
                              hipStream_t stream) {
  (void)in_sizes; (void)n_in; (void)out_size; (void)ws_size;
  const int* tokens = (const int*)d_in[0];
  const int* lengths = (const int*)d_in[1];
  const float* Wemb = (const float*)d_in[2];
  const float* Wih_f = (const float*)d_in[3];
  const float* Whh_f = (const float*)d_in[4];
  const float* b_f = (const float*)d_in[5];
  const float* Wih_b = (const float*)d_in[6];
  const float* Whh_b = (const float*)d_in[7];
  const float* b_b = (const float*)d_in[8];
  const float* h0 = (const float*)d_in[9];
  const float* c0 = (const float*)d_in[10];
  const float* Wout = (const float*)d_in[11];
  const float* bout = (const float*)d_in[12];
  const float* trans = (const float*)d_in[13];
  char* ws = (char*)d_ws;
  float* out = (float*)d_out;

  int prep_items = 2 * NT16 * KC_TOT * 64 + 2 * B_ * H_ + S_ * B_ * (KPADX / 8)
                 + 2 * (S_ * B_ * H_ * 2) / 16 + NBLK;
  hipLaunchKernelGGL(prep_kernel, dim3((prep_items + 255) / 256), dim3(256), 0, stream,
                     Wih_f, Whh_f, Wih_b, Whh_b, h0, tokens, Wemb, ws);
  hipLaunchKernelGGL(lstm_persist, dim3(NBLK), dim3(512), 0, stream, b_f, b_b, c0, ws);
  hipLaunchKernelGGL(feats_kernel, dim3(S_), dim3(256), 0, stream, Wout, bout, ws);
  hipLaunchKernelGGL(crf_kernel, dim3(B_), dim3(64), 0, stream, lengths, trans, ws);
  hipLaunchKernelGGL(final_kernel, dim3(1), dim3(64), 0, stream, ws, out);
}

// Round 7
// 1452.977 us; speedup vs baseline: 14.3744x; 14.3744x over previous
//
#include <hip/hip_runtime.h>
#include <hip/hip_bf16.h>

// ---------------------------------------------------------------------------
// BiLSTM (persistent bf16-MFMA kernel, register-resident weights + cell state,
// BARRIER-FREE data-flow sync: consumers poll sentinel-initialized h slots;
// producers fire-and-forget stores) + CRF forward.
// Base = round-4's proven 256-block x 256-thread design (932us, passed).
// ONE change this revision: chunk0-first two-phase poll with BOUNDED spin
// loops and a permanent per-thread agent-scope fallback (wdog). A thread's 4
// h chunks share col16 -> same producer block, so spin on chunk0 only (4KB
// per block-round instead of 16KB), then single-shot chunks 1-3. Bounded
// loops guarantee forward progress under ANY coherence behavior (strictly
// more robust than round 4's unbounded sc0 spin).
constexpr int B_ = 64, S_ = 512, E_ = 300, H_ = 512, T_ = 12;
constexpr int G4 = 4 * H_;          // 2048 gate rows
constexpr int KPADX = 320;          // E padded to 320 (zeros 300..319)
constexpr int KTOT = KPADX + H_;    // 832 total K (x | h)
constexpr int KC_TOT = KTOT / 32;   // 26 MFMA k-chunks
constexpr int KC_X = KPADX / 32;    // 10 x-only chunks (h-independent)
constexpr int NT16 = G4 / 16;       // 128 16-wide n tiles
constexpr float NEGV = -10000.0f;
constexpr int ASTR = 840;           // LDS A-row stride in shorts (832 + 8)
constexpr unsigned SENT = 0xFFFFFFFFu;  // sentinel dword (bf16 pair = -NaN,-NaN)

typedef __attribute__((ext_vector_type(8))) short bf16x8_t;
typedef __attribute__((ext_vector_type(4))) float f32x4_t;
typedef __attribute__((ext_vector_type(4))) unsigned u32x4_t;

// ---- workspace layout (bytes) ---------------------------------------------
constexpr size_t WC_OFF = 0;
constexpr size_t WC_BYTES = (size_t)2 * NT16 * KC_TOT * 64 * 8 * 2;  // 6,815,744
constexpr size_t XC_OFF = WC_OFF + WC_BYTES;
constexpr size_t XC_BYTES = (size_t)S_ * B_ * KPADX * 2;             // 20,971,520
constexpr size_t HH_OFF = XC_OFF + XC_BYTES;
constexpr size_t HH_BYTES = (size_t)2 * (S_ + 1) * B_ * H_ * 2;      // 67,239,936
constexpr size_t FE_OFF = HH_OFF + HH_BYTES;
constexpr size_t FE_BYTES = (size_t)S_ * B_ * T_ * 4;                // 1,572,864
constexpr size_t LSE_OFF = FE_OFF + FE_BYTES;
// CHK: 256 u32 placement-check slots INSIDE the FE region (feats_kernel runs
// after lstm_persist and fully rewrites FE, so this costs no workspace).
constexpr size_t CHK_OFF = FE_OFF;

// raw barrier: order LDS only; leave global loads in flight (no vmcnt drain).
#define BAR_LDS() do {                                         \
    asm volatile("s_waitcnt lgkmcnt(0)" ::: "memory");         \
    __builtin_amdgcn_s_barrier();                              \
    __builtin_amdgcn_sched_barrier(0);                         \
  } while (0)

// ---------------------------------------------------------------------------
// prep: (1) weights -> bf16 MFMA B-fragment order; (2) h0 -> bf16 h_hist slot
// 0; (3) embedding gather xc[s][b][320] bf16; (4) sentinel-fill hh slots 1..S;
// (5) sentinel-fill the 256-entry XCC placement-check array (in FE region).
__global__ void prep_kernel(const float* __restrict__ Wih_f, const float* __restrict__ Whh_f,
                            const float* __restrict__ Wih_b, const float* __restrict__ Whh_b,
                            const float* __restrict__ h0,
                            const int* __restrict__ tokens, const float* __restrict__ Wemb,
                            char* __restrict__ ws) {
  __hip_bfloat16* wc = (__hip_bfloat16*)(ws + WC_OFF);
  __hip_bfloat16* xc = (__hip_bfloat16*)(ws + XC_OFF);
  __hip_bfloat16* hh = (__hip_bfloat16*)(ws + HH_OFF);
  const int WCN = 2 * NT16 * KC_TOT * 64;   // 425,984
  const int H0N = 2 * B_ * H_;              // 65,536
  const int XCN = S_ * B_ * (KPADX / 8);    // 1,310,720
  const int SFD = (S_ * B_ * H_ * 2) / 16;  // 2,097,152 uint4 per dir
  int idx = blockIdx.x * 256 + threadIdx.x;
  if (idx < WCN) {
    int lane = idx & 63;
    int r = idx >> 6;
    int kc = r % KC_TOT; r /= KC_TOT;
    int tt = r % NT16;
    int dir = r / NT16;
    int n16 = lane & 15, quad = lane >> 4;
    int nt = tt >> 2, gate = tt & 3;
    int j = gate * H_ + nt * 16 + n16;   // original gate row
    int k0 = kc * 32 + quad * 8;
    const float* Wih = dir ? Wih_b : Wih_f;
    const float* Whh = dir ? Whh_b : Whh_f;
    __hip_bfloat16* dst = wc + (size_t)idx * 8;
    #pragma unroll
    for (int jj = 0; jj < 8; jj++) {
      int k = k0 + jj;
      float f;
      if (k < E_) f = Wih[(size_t)j * E_ + k];
      else if (k < KPADX) f = 0.f;
      else f = Whh[(size_t)j * H_ + (k - KPADX)];
      dst[jj] = __float2bfloat16(f);
    }
  } else if (idx < WCN + H0N) {
    int i = idx - WCN;                       // dir*B*H + b*H + h
    int dir = i / (B_ * H_), rem = i % (B_ * H_);
    hh[(size_t)dir * (S_ + 1) * B_ * H_ + rem] = __float2bfloat16(h0[i]);
  } else if (idx < WCN + H0N + XCN) {
    int i = idx - WCN - H0N;                 // sb*40 + c8
    int c8 = i % 40, sb = i / 40;            // sb = s*B + b
    int s = sb >> 6, b = sb & 63;
    int k0 = c8 * 8;
    const float* src = Wemb + (size_t)tokens[(size_t)b * S_ + s] * E_;
    __hip_bfloat16 v[8];
    if (k0 + 8 <= E_) {
      float4 f0 = *(const float4*)(src + k0);
      float4 f1 = *(const float4*)(src + k0 + 4);
      v[0] = __float2bfloat16(f0.x); v[1] = __float2bfloat16(f0.y);
      v[2] = __float2bfloat16(f0.z); v[3] = __float2bfloat16(f0.w);
      v[4] = __float2bfloat16(f1.x); v[5] = __float2bfloat16(f1.y);
      v[6] = __float2bfloat16(f1.z); v[7] = __float2bfloat16(f1.w);
    } else {
      #pragma unroll
      for (int jj = 0; jj < 8; jj++) {
        int k = k0 + jj;
        v[jj] = __float2bfloat16(k < E_ ? src[k] : 0.f);
      }
    }
    *(uint4*)(xc + (size_t)sb * KPADX + k0) = *(const uint4*)v;
  } else if (idx < WCN + H0N + XCN + 2 * SFD) {
    int i = idx - WCN - H0N - XCN;
    int dir = i / SFD, j = i % SFD;
    // sentinel-fill hh[dir][1..S][*][*]
    uint4* dst = (uint4*)(hh + (size_t)dir * (S_ + 1) * B_ * H_ + B_ * H_);
    uint4 sv; sv.x = SENT; sv.y = SENT; sv.z = SENT; sv.w = SENT;
    dst[j] = sv;
  } else if (idx < WCN + H0N + XCN + 2 * SFD + 256) {
    ((unsigned*)(ws + CHK_OFF))[idx - (WCN + H0N + XCN + 2 * SFD)] = SENT;
  }
}

// ---------------------------------------------------------------------------
// Persistent BiLSTM. grid = 256 = group(8 = dir x mt, == bid&7 -> XCD) x
// nt(32 = bid>>3). block = 256. Weights in registers; cell state in a
// register. Consumers poll h(s) 16B chunks (sentinel-initialized, sc0 =
// XCD-local L2); producers fire-and-forget sc0 dword stores.
__launch_bounds__(256, 1)
__global__ void lstm_persist(const float* __restrict__ bias_f,
                             const float* __restrict__ bias_b,
                             const float* __restrict__ c0,
                             char* __restrict__ ws) {
  __shared__ short pool[16 * ASTR];      // 26,880 B A-tile
  __shared__ float gl[4 * 16 * 17];      // 4,352 B gate exchange
  const int bid = blockIdx.x;
  // --- XCD-local remap: group g = bid&7 (round-robin -> one XCD per group) ---
  const int g = bid & 7, nt = bid >> 3, dir = g >> 2, mt = g & 3;
  const int tid = threadIdx.x, lane = tid & 63, wv = tid >> 6;
  const int quad = lane >> 4, l16 = lane & 15;
  const __hip_bfloat16* wc = (const __hip_bfloat16*)(ws + WC_OFF);
  const __hip_bfloat16* xc = (const __hip_bfloat16*)(ws + XC_OFF);
  const __hip_bfloat16* hhb = (const __hip_bfloat16*)(ws + HH_OFF);
  unsigned* hh_u = (unsigned*)(ws + HH_OFF);

  // --- load B fragments into registers, once ---
  bf16x8_t bfr[KC_TOT];
  #pragma unroll
  for (int kc = 0; kc < KC_TOT; kc++) {
    size_t boff = (((size_t)dir * NT16 + (nt * 4 + wv)) * KC_TOT + kc) * 64 + lane;
    bfr[kc] = *(const bf16x8_t*)(wc + boff * 8);
  }
  // --- per-thread cell state + biases ---
  const int bo = tid >> 4, hl = tid & 15;       // batch-offset, h-offset
  const int b = mt * 16 + bo, hg = nt * 16 + hl;
  float c = c0[(size_t)(dir * B_ + b) * H_ + hg];
  const float* bias = dir ? bias_b : bias_f;
  const float bi_i = bias[0 * H_ + hg], bi_f = bias[1 * H_ + hg];
  const float bi_g = bias[2 * H_ + hg], bi_o = bias[3 * H_ + hg];

  // --- placement check: publish XCC id, poll all 256, decide uniformly ------
  int fastu;
  {
    unsigned* chk = (unsigned*)(ws + CHK_OFF);
    unsigned* chkl = (unsigned*)pool;          // reuse LDS as scratch
    if (tid == 0) {
      unsigned xcc;
      asm volatile("s_getreg_b32 %0, hwreg(HW_REG_XCC_ID)" : "=s"(xcc));
      __hip_atomic_store(chk + bid, xcc & 0xFu, __ATOMIC_RELAXED,
                         __HIP_MEMORY_SCOPE_AGENT);
    }
    unsigned myv;
    for (;;) {
      myv = __hip_atomic_load(chk + tid, __ATOMIC_RELAXED, __HIP_MEMORY_SCOPE_AGENT);
      if (myv != SENT) break;
      __builtin_amdgcn_s_sleep(4);
    }
    chkl[tid] = myv;
    __syncthreads();
    bool f = true;
    unsigned mask = 0;
    for (int gg = 0; gg < 8; gg++) {
      unsigned v0 = chkl[gg];
      f = f && (v0 < 32u);
      mask |= (1u << (v0 & 31u));
      for (int m = 1; m < 32; m++) f = f && (chkl[gg + 8 * m] == v0);
    }
    f = f && (__popc(mask) == 8);   // 8 groups on 8 DISTINCT XCDs (garbage guard)
    fastu = __builtin_amdgcn_readfirstlane(f ? 1 : 0);
    __syncthreads();                // before pool reuse below
  }

  // --- pre-stage x(0) into pool x-region ---
  {
    int spos0 = dir ? (S_ - 1) : 0;
    for (int i = tid; i < 16 * 40; i += 256) {
      int row = i / 40, c8 = i % 40;
      *(uint4*)(pool + row * ASTR + c8 * 8) =
          *(const uint4*)(xc + ((size_t)spos0 * B_ + mt * 16 + row) * KPADX + c8 * 8);
    }
  }
  __syncthreads();   // x(0) visible before first x-MFMA phase

  // poll/stage map: 16KB h tile = 1024 16B chunks; thread owns chunks
  // tid + k*256 (k=0..3): row = i>>6, col16 = i&63 — all 4 share col16, so
  // ALL FOUR are written by the same producer block (nt = col16/2).
  int wdog = 0;   // latches 1 if the sc0 poll ever exhausts its budget
  for (int s = 0; s < S_; s++) {
    // --- 1. x-part MFMAs (h-independent) ---
    f32x4_t acc = (f32x4_t)(0.f);
    #pragma unroll
    for (int kc = 0; kc < KC_X; kc++) {
      bf16x8_t af = *(const bf16x8_t*)(pool + l16 * ASTR + kc * 32 + quad * 8);
      acc = __builtin_amdgcn_mfma_f32_16x16x32_bf16(af, bfr[kc], acc, 0, 0, 0);
    }
    // --- 2. poll h(s): chunk0-first two-phase sentinel poll (sc0), bounded ---
    const u32x4_t* pbase = (const u32x4_t*)(hhb +
        ((size_t)(dir * (S_ + 1) + s) * B_ + mt * 16) * H_);
    u32x4_t t0, t1, t2, t3;
    bool got = false;
    if (fastu && !wdog) {
      // phase 1: spin on chunk0 only (4KB/block/round)
      const u32x4_t* q0 = pbase + tid;
      bool ok0 = false;
      for (int tries = 0; tries < 16384; ++tries) {
        asm volatile("global_load_dwordx4 %0, %1, off sc0\n\t"
                     "s_waitcnt vmcnt(0)"
                     : "=&v"(t0) : "v"(q0) : "memory");
        if (t0[0] != SENT && t0[1] != SENT && t0[2] != SENT && t0[3] != SENT) {
          ok0 = true; break;
        }
        __builtin_amdgcn_s_sleep(1);
      }
      if (ok0) {
        // phase 2: chunks 1-3 (same producer block; usually already there)
        const u32x4_t* q1 = pbase + tid + 256;
        const u32x4_t* q2 = pbase + tid + 512;
        const u32x4_t* q3 = pbase + tid + 768;
        for (int tries = 0; tries < 16384; ++tries) {
          asm volatile("global_load_dwordx4 %0, %3, off sc0\n\t"
                       "global_load_dwordx4 %1, %4, off sc0\n\t"
                       "global_load_dwordx4 %2, %5, off sc0\n\t"
                       "s_waitcnt vmcnt(0)"
                       : "=&v"(t1), "=&v"(t2), "=&v"(t3)
                       : "v"(q1), "v"(q2), "v"(q3)
                       : "memory");
          bool ok = t1[0] != SENT && t1[1] != SENT && t1[2] != SENT && t1[3] != SENT &&
                    t2[0] != SENT && t2[1] != SENT && t2[2] != SENT && t2[3] != SENT &&
                    t3[0] != SENT && t3[1] != SENT && t3[2] != SENT && t3[3] != SENT;
          if (ok) { got = true; break; }
          __builtin_amdgcn_s_sleep(1);
        }
      }
      if (!got) wdog = 1;   // permanent fallback for this thread
    }
    if (!got) {
      // agent-scope sentinel poll (device-coherent, unconditionally safe)
      const unsigned long long* qq = (const unsigned long long*)pbase;
      u32x4_t tt[4];
      bool ok = false;
      while (!ok) {
        ok = true;
        #pragma unroll
        for (int k = 0; k < 4; k++) {
          int i = tid + k * 256;
          unsigned long long a0 = __hip_atomic_load(qq + 2 * i, __ATOMIC_RELAXED,
                                                    __HIP_MEMORY_SCOPE_AGENT);
          unsigned long long a1 = __hip_atomic_load(qq + 2 * i + 1, __ATOMIC_RELAXED,
                                                    __HIP_MEMORY_SCOPE_AGENT);
          tt[k][0] = (unsigned)a0; tt[k][1] = (unsigned)(a0 >> 32);
          tt[k][2] = (unsigned)a1; tt[k][3] = (unsigned)(a1 >> 32);
          ok = ok && tt[k][0] != SENT && tt[k][1] != SENT &&
                     tt[k][2] != SENT && tt[k][3] != SENT;
        }
        if (!ok) __builtin_amdgcn_s_sleep(1);
      }
      t0 = tt[0]; t1 = tt[1]; t2 = tt[2]; t3 = tt[3];
    }
    // --- 3. issue x(s+1) prefetch loads into VGPRs (consumed at step 9) ---
    u32x4_t xpf0, xpf1, xpf2;
    const bool xok = (s + 1 < S_);
    if (xok) {
      int sposn = dir ? (S_ - 2 - s) : (s + 1);
      const u32x4_t* xq = (const u32x4_t*)xc;   // 8 bf16 per u32x4
      int i0 = tid, i1 = tid + 256, i2 = tid + 512;
      xpf0 = xq[((size_t)sposn * B_ + mt * 16 + i0 / 40) * 40 + i0 % 40];
      xpf1 = xq[((size_t)sposn * B_ + mt * 16 + i1 / 40) * 40 + i1 % 40];
      if (i2 < 640)
        xpf2 = xq[((size_t)sposn * B_ + mt * 16 + i2 / 40) * 40 + i2 % 40];
    }
    // --- 4. stage h(s) -> LDS h-region (4 x b128) ---
    {
      int r0 = tid >> 6, c0v = tid & 63;
      *(u32x4_t*)(pool + r0 * ASTR + KPADX + c0v * 8) = t0;
      int i1 = tid + 256; int r1 = i1 >> 6, c1v = i1 & 63;
      *(u32x4_t*)(pool + r1 * ASTR + KPADX + c1v * 8) = t1;
      int i2 = tid + 512; int r2 = i2 >> 6, c2v = i2 & 63;
      *(u32x4_t*)(pool + r2 * ASTR + KPADX + c2v * 8) = t2;
      int i3 = tid + 768; int r3 = i3 >> 6, c3v = i3 & 63;
      *(u32x4_t*)(pool + r3 * ASTR + KPADX + c3v * 8) = t3;
    }
    BAR_LDS();   // B1: h tile staged (LDS-only wait; xpf loads stay in flight)
    // --- 5. h-part MFMAs (same accumulation order: kc 10..25) ---
    #pragma unroll
    for (int kc = KC_X; kc < KC_TOT; kc++) {
      bf16x8_t af = *(const bf16x8_t*)(pool + l16 * ASTR + kc * 32 + quad * 8);
      acc = __builtin_amdgcn_mfma_f32_16x16x32_bf16(af, bfr[kc], acc, 0, 0, 0);
    }
    // --- 6. gate exchange: C/D row = quad*4+r (batch-offset), col = l16 ---
    #pragma unroll
    for (int r = 0; r < 4; r++)
      gl[(wv * 16 + quad * 4 + r) * 17 + l16] = acc[r];
    BAR_LDS();   // B2: gl ready + all pool A-reads complete
    // --- 7. elementwise cell update (c in register) ---
    float gi = gl[(0 * 16 + bo) * 17 + hl] + bi_i;
    float gf = gl[(1 * 16 + bo) * 17 + hl] + bi_f;
    float gg = gl[(2 * 16 + bo) * 17 + hl] + bi_g;
    float go = gl[(3 * 16 + bo) * 17 + hl] + bi_o;
    float ii = 1.f / (1.f + __expf(-gi));
    float ff = 1.f / (1.f + __expf(-gf));
    float gt = 1.f - 2.f / (1.f + __expf(2.f * gg));   // tanh
    float oo = 1.f / (1.f + __expf(-go));
    c = ff * c + ii * gt;
    float hv2 = oo * (1.f - 2.f / (1.f + __expf(2.f * c)));
    // --- 8. h store: pack 2 bf16 -> one sc0 dword store; fire-and-forget ---
    float hn = __shfl_xor(hv2, 1, 64);    // partner shares (bo, hl^1)
    if ((hl & 1) == 0) {
      unsigned short ulo = __builtin_bit_cast(unsigned short, __float2bfloat16(hv2));
      unsigned short uhi = __builtin_bit_cast(unsigned short, __float2bfloat16(hn));
      unsigned pk = ((unsigned)uhi << 16) | (unsigned)ulo;
      size_t uidx = (((size_t)(dir * (S_ + 1) + s + 1) * B_ + b) * H_ + hg) >> 1;
      if (fastu) {
        // expcnt(0) inside the asm: VMEM stores read their data VGPR
        // asynchronously; without it the compiler may reuse pk's register
        // before the store consumes it (round-0 hang mechanism).
        asm volatile("global_store_dword %0, %1, off sc0\n\t"
                     "s_waitcnt expcnt(0)"
                     :: "v"(hh_u + uidx), "v"(pk) : "memory");
      } else {
        __hip_atomic_store(hh_u + uidx, pk, __ATOMIC_RELAXED,
                           __HIP_MEMORY_SCOPE_AGENT);
      }
    }
    // --- 9. write prefetched x(s+1) into pool x-region (loads long landed) ---
    if (xok) {
      int i0 = tid, i1 = tid + 256, i2 = tid + 512;
      *(u32x4_t*)(pool + (i0 / 40) * ASTR + (i0 % 40) * 8) = xpf0;
      *(u32x4_t*)(pool + (i1 / 40) * ASTR + (i1 % 40) * 8) = xpf1;
      if (i2 < 640)
        *(u32x4_t*)(pool + (i2 / 40) * ASTR + (i2 % 40) * 8) = xpf2;
    }
    BAR_LDS();   // B3: x(s+1) staged for next iteration's x-MFMAs
  }
}

// ---------------------------------------------------------------------------
// feats[(b*S+s)*T + t] = [hf(s) | hb(s)] . W_out[t,:] + b_out[t]. block per s.
// Output layout [b][s][t] so the CRF scan reads contiguously per batch.
// LDS tile stride padded 1024->1032 to break the 4-way t-lane bank conflict.
__launch_bounds__(256)
__global__ void feats_kernel(const float* __restrict__ Wout,
                             const float* __restrict__ bout,
                             char* __restrict__ ws) {
  __shared__ float wl[12 * 1032];   // 49,536 B
  const int s = blockIdx.x, tid = threadIdx.x;
  for (int i = tid; i < 12 * 1024 / 4; i += 256) {
    int idx4 = i * 4;
    int t = idx4 >> 10, k = idx4 & 1023;
    *(float4*)(wl + t * 1032 + k) = *(const float4*)(Wout + idx4);
  }
  __syncthreads();
  const __hip_bfloat16* hh = (const __hip_bfloat16*)(ws + HH_OFF);
  float* fe = (float*)(ws + FE_OFF);
  int b = tid >> 2, tg = tid & 3, t0 = tg * 3;
  const __hip_bfloat16* hf = hh + (size_t)(0 * (S_ + 1) + s + 1) * B_ * H_ + (size_t)b * H_;
  const __hip_bfloat16* hb = hh + (size_t)(1 * (S_ + 1) + (S_ - s)) * B_ * H_ + (size_t)b * H_;
  float a0 = 0.f, a1 = 0.f, a2 = 0.f;
  for (int half = 0; half < 2; half++) {
    const __hip_bfloat16* hp = half ? hb : hf;
    int wof = half * 512;
    for (int k = 0; k < 512; k += 8) {
      uint4 raw = *(const uint4*)(hp + k);
      const __hip_bfloat16* hv = (const __hip_bfloat16*)&raw;
      float hfl[8];
      #pragma unroll
      for (int j = 0; j < 8; j++) hfl[j] = __bfloat162float(hv[j]);
      #pragma unroll
      for (int j = 0; j < 8; j++) {
        a0 += hfl[j] * wl[(t0 + 0) * 1032 + wof + k + j];
        a1 += hfl[j] * wl[(t0 + 1) * 1032 + wof + k + j];
        a2 += hfl[j] * wl[(t0 + 2) * 1032 + wof + k + j];
      }
    }
  }
  float* o = fe + ((size_t)b * S_ + s) * T_;
  o[t0 + 0] = a0 + bout[t0 + 0];
  o[t0 + 1] = a1 + bout[t0 + 1];
  o[t0 + 2] = a2 + bout[t0 + 2];
}

// ---------------------------------------------------------------------------
// CRF forward scan: one wave per batch element; lane = next-tag (<12).
// Software-pipelined: load feat(s+1) while computing step s.
__launch_bounds__(64)
__global__ void crf_kernel(const int* __restrict__ lengths,
                           const float* __restrict__ trans,
                           char* __restrict__ ws) {
  const int b = blockIdx.x, lane = threadIdx.x;
  const float* fe = (const float*)(ws + FE_OFF);
  float* lse = (float*)(ws + LSE_OFF);
  const float* fb = fe + (size_t)b * S_ * T_;
  float tr[12];
  #pragma unroll
  for (int p = 0; p < 12; p++) tr[p] = (lane < 12) ? trans[lane * 12 + p] : 0.f;
  float tstop = (lane < 12) ? trans[11 * 12 + lane] : 0.f;  // STOP row
  float alpha = (lane == 10) ? 0.f : NEGV;                  // START tag
  const int len = lengths[b];
  float feat = (lane < 12) ? fb[lane] : 0.f;
  for (int s = 0; s < S_; s++) {
    float fn = (lane < 12 && s + 1 < S_) ? fb[(size_t)(s + 1) * T_ + lane] : 0.f;
    float av[12];
    #pragma unroll
    for (int p = 0; p < 12; p++) av[p] = __shfl(alpha, p, 64) + tr[p];
    float mx = av[0];
    #pragma unroll
    for (int p = 1; p < 12; p++) mx = fmaxf(mx, av[p]);
    float sum = 0.f;
    #pragma unroll
    for (int p = 0; p < 12; p++) sum += __expf(av[p] - mx);
    float nw = mx + __logf(sum) + feat;
    if (s < len && lane < 12) alpha = nw;
    feat = fn;
  }
  float tv = (lane < 12) ? (alpha + tstop) : -3.0e38f;
  float mx = tv;
  #pragma unroll
  for (int off = 32; off > 0; off >>= 1) mx = fmaxf(mx, __shfl_xor(mx, off, 64));
  float sum = __expf(tv - mx);
  #pragma unroll
  for (int off = 32; off > 0; off >>= 1) sum += __shfl_xor(sum, off, 64);
  if (lane == 0) lse[b] = mx + __logf(sum);
}

__global__ void final_kernel(char* __restrict__ ws, float* __restrict__ out) {
  const float* lse = (const float*)(ws + LSE_OFF);
  float v = lse[threadIdx.x];
  #pragma unroll
  for (int off = 32; off > 0; off >>= 1) v += __shfl_xor(v, off, 64);
  if (threadIdx.x == 0) out[0] = v * (1.f / 64.f);
}

// ---------------------------------------------------------------------------
extern "C" void kernel_launch(void* const* d_in, const int* in_sizes, int n_in,
                              void* d_out, int out_size, void* d_ws, size_t ws_size,
                              hipStream_t stream) {
  (void)in_sizes; (void)n_in; (void)out_size; (void)ws_size;
  const int* tokens = (const int*)d_in[0];
  const int* lengths = (const int*)d_in[1];
  const float* Wemb = (const float*)d_in[2];
  const float* Wih_f = (const float*)d_in[3];
  const float* Whh_f = (const float*)d_in[4];
  const float* b_f = (const float*)d_in[5];
  const float* Wih_b = (const float*)d_in[6];
  const float* Whh_b = (const float*)d_in[7];
  const float* b_b = (const float*)d_in[8];
  const float* h0 = (const float*)d_in[9];
  const float* c0 = (const float*)d_in[10];
  const float* Wout = (const float*)d_in[11];
  const float* bout = (const float*)d_in[12];
  const float* trans = (const float*)d_in[13];
  char* ws = (char*)d_ws;
  float* out = (float*)d_out;

  int prep_items = 2 * NT16 * KC_TOT * 64 + 2 * B_ * H_ + S_ * B_ * (KPADX / 8)
                 + 2 * (S_ * B_ * H_ * 2) / 16 + 256;
  hipLaunchKernelGGL(prep_kernel, dim3((prep_items + 255) / 256), dim3(256), 0, stream,
                     Wih_f, Whh_f, Wih_b, Whh_b, h0, tokens, Wemb, ws);
  hipLaunchKernelGGL(lstm_persist, dim3(256), dim3(256), 0, stream, b_f, b_b, c0, ws);
  hipLaunchKernelGGL(feats_kernel, dim3(S_), dim3(256), 0, stream, Wout, bout, ws);
  hipLaunchKernelGGL(crf_kernel, dim3(B_), dim3(64), 0, stream, lengths, trans, ws);
  hipLaunchKernelGGL(final_kernel, dim3(1), dim3(64), 0, stream, ws, out);
}

// Round 8
// 1324.559 us; speedup vs baseline: 15.7680x; 1.0970x over previous
//
#include <hip/hip_runtime.h>
#include <hip/hip_bf16.h>

// ---------------------------------------------------------------------------
// BiLSTM (persistent bf16-MFMA kernel, register-resident weights + cell state,
// BARRIER-FREE data-flow sync: consumers poll sentinel-initialized h slots;
// producers fire-and-forget stores) + CRF forward.
// Base = round-4's proven 256x256 design (932us). Changes this revision:
//  (a) poll reverted to round-4's FUSED 4-chunk sentinel poll (round-7's
//      chunk0-first split regressed: it separated detect from data and added
//      an L2 round trip per step), kept bounded + wdog permanent fallback;
//  (b) barrier B2 DELETED: B-fragment columns reassigned so each wave's
//      16x16 output tile = 4 gates x 4 h-columns (prep: j = (c>>2)*H +
//      nt*16 + wv*4 + (c&3)) -> the gate transpose becomes WAVE-PRIVATE
//      (4 ds_write -> lgkmcnt(0) -> 4 ds_read, no s_barrier). Each output
//      element's k-accumulation order is unchanged -> bit-identical numerics.
//      Inter-block chain loses one barrier + its skew.
constexpr int B_ = 64, S_ = 512, E_ = 300, H_ = 512, T_ = 12;
constexpr int G4 = 4 * H_;          // 2048 gate rows
constexpr int KPADX = 320;          // E padded to 320 (zeros 300..319)
constexpr int KTOT = KPADX + H_;    // 832 total K (x | h)
constexpr int KC_TOT = KTOT / 32;   // 26 MFMA k-chunks
constexpr int KC_X = KPADX / 32;    // 10 x-only chunks (h-independent)
constexpr int NT16 = G4 / 16;       // 128 16-wide n tiles
constexpr float NEGV = -10000.0f;
constexpr int ASTR = 840;           // LDS A-row stride in shorts (832 + 8)
constexpr unsigned SENT = 0xFFFFFFFFu;  // sentinel dword (bf16 pair = -NaN,-NaN)
constexpr int GLW = 16 * 17;        // per-wave gate-transpose region (floats)

typedef __attribute__((ext_vector_type(8))) short bf16x8_t;
typedef __attribute__((ext_vector_type(4))) float f32x4_t;
typedef __attribute__((ext_vector_type(4))) unsigned u32x4_t;

// ---- workspace layout (bytes) ---------------------------------------------
constexpr size_t WC_OFF = 0;
constexpr size_t WC_BYTES = (size_t)2 * NT16 * KC_TOT * 64 * 8 * 2;  // 6,815,744
constexpr size_t XC_OFF = WC_OFF + WC_BYTES;
constexpr size_t XC_BYTES = (size_t)S_ * B_ * KPADX * 2;             // 20,971,520
constexpr size_t HH_OFF = XC_OFF + XC_BYTES;
constexpr size_t HH_BYTES = (size_t)2 * (S_ + 1) * B_ * H_ * 2;      // 67,239,936
constexpr size_t FE_OFF = HH_OFF + HH_BYTES;
constexpr size_t FE_BYTES = (size_t)S_ * B_ * T_ * 4;                // 1,572,864
constexpr size_t LSE_OFF = FE_OFF + FE_BYTES;
// CHK: 256 u32 placement-check slots INSIDE the FE region (feats_kernel runs
// after lstm_persist and fully rewrites FE, so this costs no workspace).
constexpr size_t CHK_OFF = FE_OFF;

// raw barrier: order LDS only; leave global loads in flight (no vmcnt drain).
#define BAR_LDS() do {                                         \
    asm volatile("s_waitcnt lgkmcnt(0)" ::: "memory");         \
    __builtin_amdgcn_s_barrier();                              \
    __builtin_amdgcn_sched_barrier(0);                         \
  } while (0)

// ---------------------------------------------------------------------------
// prep: (1) weights -> bf16 MFMA B-fragment order (4 gates x 4 hcols per
// tile); (2) h0 -> bf16 h_hist slot 0; (3) embedding gather xc[s][b][320]
// bf16; (4) sentinel-fill hh slots 1..S; (5) sentinel-fill the 256-entry XCC
// placement-check array (in FE region).
__global__ void prep_kernel(const float* __restrict__ Wih_f, const float* __restrict__ Whh_f,
                            const float* __restrict__ Wih_b, const float* __restrict__ Whh_b,
                            const float* __restrict__ h0,
                            const int* __restrict__ tokens, const float* __restrict__ Wemb,
                            char* __restrict__ ws) {
  __hip_bfloat16* wc = (__hip_bfloat16*)(ws + WC_OFF);
  __hip_bfloat16* xc = (__hip_bfloat16*)(ws + XC_OFF);
  __hip_bfloat16* hh = (__hip_bfloat16*)(ws + HH_OFF);
  const int WCN = 2 * NT16 * KC_TOT * 64;   // 425,984
  const int H0N = 2 * B_ * H_;              // 65,536
  const int XCN = S_ * B_ * (KPADX / 8);    // 1,310,720
  const int SFD = (S_ * B_ * H_ * 2) / 16;  // 2,097,152 uint4 per dir
  int idx = blockIdx.x * 256 + threadIdx.x;
  if (idx < WCN) {
    int lane = idx & 63;
    int r = idx >> 6;
    int kc = r % KC_TOT; r /= KC_TOT;
    int tt = r % NT16;
    int dir = r / NT16;
    int n16 = lane & 15, quad = lane >> 4;
    int nt = tt >> 2, wvq = tt & 3;
    // column c = n16 = gate*4 + hcl  ->  original gate row:
    int j = (n16 >> 2) * H_ + nt * 16 + wvq * 4 + (n16 & 3);
    int k0 = kc * 32 + quad * 8;
    const float* Wih = dir ? Wih_b : Wih_f;
    const float* Whh = dir ? Whh_b : Whh_f;
    __hip_bfloat16* dst = wc + (size_t)idx * 8;
    #pragma unroll
    for (int jj = 0; jj < 8; jj++) {
      int k = k0 + jj;
      float f;
      if (k < E_) f = Wih[(size_t)j * E_ + k];
      else if (k < KPADX) f = 0.f;
      else f = Whh[(size_t)j * H_ + (k - KPADX)];
      dst[jj] = __float2bfloat16(f);
    }
  } else if (idx < WCN + H0N) {
    int i = idx - WCN;                       // dir*B*H + b*H + h
    int dir = i / (B_ * H_), rem = i % (B_ * H_);
    hh[(size_t)dir * (S_ + 1) * B_ * H_ + rem] = __float2bfloat16(h0[i]);
  } else if (idx < WCN + H0N + XCN) {
    int i = idx - WCN - H0N;                 // sb*40 + c8
    int c8 = i % 40, sb = i / 40;            // sb = s*B + b
    int s = sb >> 6, b = sb & 63;
    int k0 = c8 * 8;
    const float* src = Wemb + (size_t)tokens[(size_t)b * S_ + s] * E_;
    __hip_bfloat16 v[8];
    if (k0 + 8 <= E_) {
      float4 f0 = *(const float4*)(src + k0);
      float4 f1 = *(const float4*)(src + k0 + 4);
      v[0] = __float2bfloat16(f0.x); v[1] = __float2bfloat16(f0.y);
      v[2] = __float2bfloat16(f0.z); v[3] = __float2bfloat16(f0.w);
      v[4] = __float2bfloat16(f1.x); v[5] = __float2bfloat16(f1.y);
      v[6] = __float2bfloat16(f1.z); v[7] = __float2bfloat16(f1.w);
    } else {
      #pragma unroll
      for (int jj = 0; jj < 8; jj++) {
        int k = k0 + jj;
        v[jj] = __float2bfloat16(k < E_ ? src[k] : 0.f);
      }
    }
    *(uint4*)(xc + (size_t)sb * KPADX + k0) = *(const uint4*)v;
  } else if (idx < WCN + H0N + XCN + 2 * SFD) {
    int i = idx - WCN - H0N - XCN;
    int dir = i / SFD, j = i % SFD;
    // sentinel-fill hh[dir][1..S][*][*]
    uint4* dst = (uint4*)(hh + (size_t)dir * (S_ + 1) * B_ * H_ + B_ * H_);
    uint4 sv; sv.x = SENT; sv.y = SENT; sv.z = SENT; sv.w = SENT;
    dst[j] = sv;
  } else if (idx < WCN + H0N + XCN + 2 * SFD + 256) {
    ((unsigned*)(ws + CHK_OFF))[idx - (WCN + H0N + XCN + 2 * SFD)] = SENT;
  }
}

// ---------------------------------------------------------------------------
// Persistent BiLSTM. grid = 256 = group(8 = dir x mt, == bid&7 -> XCD) x
// nt(32 = bid>>3). block = 256. Weights in registers; cell state in a
// register. Consumers poll h(s) 16B chunks (sentinel-initialized, sc0 =
// XCD-local L2); producers fire-and-forget sc0 dword stores. Wave wv owns
// output tile = 4 gates x 4 hcols (nt*16 + wv*4 .. +3) -> gate transpose
// is wave-private (no barrier).
__launch_bounds__(256, 1)
__global__ void lstm_persist(const float* __restrict__ bias_f,
                             const float* __restrict__ bias_b,
                             const float* __restrict__ c0,
                             char* __restrict__ ws) {
  __shared__ short pool[16 * ASTR];      // 26,880 B A-tile
  __shared__ float gl[4 * GLW];          // 4,352 B per-wave gate transpose
  const int bid = blockIdx.x;
  // --- XCD-local remap: group g = bid&7 (round-robin -> one XCD per group) ---
  const int g = bid & 7, nt = bid >> 3, dir = g >> 2, mt = g & 3;
  const int tid = threadIdx.x, lane = tid & 63, wv = tid >> 6;
  const int quad = lane >> 4, l16 = lane & 15;
  const __hip_bfloat16* wc = (const __hip_bfloat16*)(ws + WC_OFF);
  const __hip_bfloat16* xc = (const __hip_bfloat16*)(ws + XC_OFF);
  const __hip_bfloat16* hhb = (const __hip_bfloat16*)(ws + HH_OFF);
  unsigned* hh_u = (unsigned*)(ws + HH_OFF);

  // --- load B fragments into registers, once ---
  bf16x8_t bfr[KC_TOT];
  #pragma unroll
  for (int kc = 0; kc < KC_TOT; kc++) {
    size_t boff = (((size_t)dir * NT16 + (nt * 4 + wv)) * KC_TOT + kc) * 64 + lane;
    bfr[kc] = *(const bf16x8_t*)(wc + boff * 8);
  }
  // --- per-thread cell-update assignment: (batch batt, hcol hg) ---
  const int batt = quad * 4 + (l16 >> 2), hcl = l16 & 3;
  const int b = mt * 16 + batt, hg = nt * 16 + wv * 4 + hcl;
  float c = c0[(size_t)(dir * B_ + b) * H_ + hg];
  const float* bias = dir ? bias_b : bias_f;
  const float bi_i = bias[0 * H_ + hg], bi_f = bias[1 * H_ + hg];
  const float bi_g = bias[2 * H_ + hg], bi_o = bias[3 * H_ + hg];

  // --- placement check: publish XCC id, poll all 256, decide uniformly ------
  int fastu;
  {
    unsigned* chk = (unsigned*)(ws + CHK_OFF);
    unsigned* chkl = (unsigned*)pool;          // reuse LDS as scratch
    if (tid == 0) {
      unsigned xcc;
      asm volatile("s_getreg_b32 %0, hwreg(HW_REG_XCC_ID)" : "=s"(xcc));
      __hip_atomic_store(chk + bid, xcc & 0xFu, __ATOMIC_RELAXED,
                         __HIP_MEMORY_SCOPE_AGENT);
    }
    unsigned myv;
    for (;;) {
      myv = __hip_atomic_load(chk + tid, __ATOMIC_RELAXED, __HIP_MEMORY_SCOPE_AGENT);
      if (myv != SENT) break;
      __builtin_amdgcn_s_sleep(4);
    }
    chkl[tid] = myv;
    __syncthreads();
    bool f = true;
    unsigned mask = 0;
    for (int gg = 0; gg < 8; gg++) {
      unsigned v0 = chkl[gg];
      f = f && (v0 < 32u);
      mask |= (1u << (v0 & 31u));
      for (int m = 1; m < 32; m++) f = f && (chkl[gg + 8 * m] == v0);
    }
    f = f && (__popc(mask) == 8);   // 8 groups on 8 DISTINCT XCDs (garbage guard)
    fastu = __builtin_amdgcn_readfirstlane(f ? 1 : 0);
    __syncthreads();                // before pool reuse below
  }

  // --- pre-stage x(0) into pool x-region ---
  {
    int spos0 = dir ? (S_ - 1) : 0;
    for (int i = tid; i < 16 * 40; i += 256) {
      int row = i / 40, c8 = i % 40;
      *(uint4*)(pool + row * ASTR + c8 * 8) =
          *(const uint4*)(xc + ((size_t)spos0 * B_ + mt * 16 + row) * KPADX + c8 * 8);
    }
  }
  __syncthreads();   // x(0) visible before first x-MFMA phase

  // poll/stage map: 16KB h tile = 1024 16B chunks; thread owns chunks
  // tid + k*256 (k=0..3): row = i>>6, col16 = i&63.
  int wdog = 0;   // latches 1 if the sc0 poll ever exhausts its budget
  for (int s = 0; s < S_; s++) {
    // --- 1. x-part MFMAs (h-independent) ---
    f32x4_t acc = (f32x4_t)(0.f);
    #pragma unroll
    for (int kc = 0; kc < KC_X; kc++) {
      bf16x8_t af = *(const bf16x8_t*)(pool + l16 * ASTR + kc * 32 + quad * 8);
      acc = __builtin_amdgcn_mfma_f32_16x16x32_bf16(af, bfr[kc], acc, 0, 0, 0);
    }
    // --- 2. poll h(s): FUSED 4-chunk sentinel poll (sc0), bounded + wdog ---
    const u32x4_t* pbase = (const u32x4_t*)(hhb +
        ((size_t)(dir * (S_ + 1) + s) * B_ + mt * 16) * H_);
    u32x4_t t0, t1, t2, t3;
    bool got = false;
    if (fastu && !wdog) {
      const u32x4_t* q0 = pbase + tid;
      const u32x4_t* q1 = pbase + tid + 256;
      const u32x4_t* q2 = pbase + tid + 512;
      const u32x4_t* q3 = pbase + tid + 768;
      for (int tries = 0; tries < 16384; ++tries) {
        asm volatile(
            "global_load_dwordx4 %0, %4, off sc0\n\t"
            "global_load_dwordx4 %1, %5, off sc0\n\t"
            "global_load_dwordx4 %2, %6, off sc0\n\t"
            "global_load_dwordx4 %3, %7, off sc0\n\t"
            "s_waitcnt vmcnt(0)"
            : "=&v"(t0), "=&v"(t1), "=&v"(t2), "=&v"(t3)
            : "v"(q0), "v"(q1), "v"(q2), "v"(q3)
            : "memory");
        bool ok = t0[0] != SENT && t0[1] != SENT && t0[2] != SENT && t0[3] != SENT &&
                  t1[0] != SENT && t1[1] != SENT && t1[2] != SENT && t1[3] != SENT &&
                  t2[0] != SENT && t2[1] != SENT && t2[2] != SENT && t2[3] != SENT &&
                  t3[0] != SENT && t3[1] != SENT && t3[2] != SENT && t3[3] != SENT;
        if (ok) { got = true; break; }
        __builtin_amdgcn_s_sleep(1);
      }
      if (!got) wdog = 1;   // permanent per-thread fallback
    }
    if (!got) {
      // agent-scope sentinel poll (device-coherent, unconditionally safe)
      const unsigned long long* qq = (const unsigned long long*)pbase;
      u32x4_t tt[4];
      bool ok = false;
      while (!ok) {
        ok = true;
        #pragma unroll
        for (int k = 0; k < 4; k++) {
          int i = tid + k * 256;
          unsigned long long a0 = __hip_atomic_load(qq + 2 * i, __ATOMIC_RELAXED,
                                                    __HIP_MEMORY_SCOPE_AGENT);
          unsigned long long a1 = __hip_atomic_load(qq + 2 * i + 1, __ATOMIC_RELAXED,
                                                    __HIP_MEMORY_SCOPE_AGENT);
          tt[k][0] = (unsigned)a0; tt[k][1] = (unsigned)(a0 >> 32);
          tt[k][2] = (unsigned)a1; tt[k][3] = (unsigned)(a1 >> 32);
          ok = ok && tt[k][0] != SENT && tt[k][1] != SENT &&
                     tt[k][2] != SENT && tt[k][3] != SENT;
        }
        if (!ok) __builtin_amdgcn_s_sleep(1);
      }
      t0 = tt[0]; t1 = tt[1]; t2 = tt[2]; t3 = tt[3];
    }
    // --- 3. issue x(s+1) prefetch loads into VGPRs (consumed at step 9) ---
    u32x4_t xpf0, xpf1, xpf2;
    const bool xok = (s + 1 < S_);
    if (xok) {
      int sposn = dir ? (S_ - 2 - s) : (s + 1);
      const u32x4_t* xq = (const u32x4_t*)xc;   // 8 bf16 per u32x4
      int i0 = tid, i1 = tid + 256, i2 = tid + 512;
      xpf0 = xq[((size_t)sposn * B_ + mt * 16 + i0 / 40) * 40 + i0 % 40];
      xpf1 = xq[((size_t)sposn * B_ + mt * 16 + i1 / 40) * 40 + i1 % 40];
      if (i2 < 640)
        xpf2 = xq[((size_t)sposn * B_ + mt * 16 + i2 / 40) * 40 + i2 % 40];
    }
    // --- 4. stage h(s) -> LDS h-region (4 x b128) ---
    {
      int r0 = tid >> 6, c0v = tid & 63;
      *(u32x4_t*)(pool + r0 * ASTR + KPADX + c0v * 8) = t0;
      int i1 = tid + 256; int r1 = i1 >> 6, c1v = i1 & 63;
      *(u32x4_t*)(pool + r1 * ASTR + KPADX + c1v * 8) = t1;
      int i2 = tid + 512; int r2 = i2 >> 6, c2v = i2 & 63;
      *(u32x4_t*)(pool + r2 * ASTR + KPADX + c2v * 8) = t2;
      int i3 = tid + 768; int r3 = i3 >> 6, c3v = i3 & 63;
      *(u32x4_t*)(pool + r3 * ASTR + KPADX + c3v * 8) = t3;
    }
    BAR_LDS();   // B1: h tile staged (LDS-only wait; xpf loads stay in flight)
    // --- 5. h-part MFMAs (same accumulation order: kc 10..25) ---
    #pragma unroll
    for (int kc = KC_X; kc < KC_TOT; kc++) {
      bf16x8_t af = *(const bf16x8_t*)(pool + l16 * ASTR + kc * 32 + quad * 8);
      acc = __builtin_amdgcn_mfma_f32_16x16x32_bf16(af, bfr[kc], acc, 0, 0, 0);
    }
    // --- 6. WAVE-PRIVATE gate transpose (no barrier): C/D row = quad*4+r
    //        (batch), col = l16 = gate*4 + hcl. Write col-major, lgkmcnt,
    //        read back 4 gates for this thread's (batt, hcl). ---
    {
      float* glw = gl + wv * GLW;
      #pragma unroll
      for (int r = 0; r < 4; r++)
        glw[l16 * 17 + quad * 4 + r] = acc[r];
      asm volatile("s_waitcnt lgkmcnt(0)" ::: "memory");
      __builtin_amdgcn_sched_barrier(0);
      float gi = glw[(0 * 4 + hcl) * 17 + batt] + bi_i;
      float gf = glw[(1 * 4 + hcl) * 17 + batt] + bi_f;
      float gg = glw[(2 * 4 + hcl) * 17 + batt] + bi_g;
      float go = glw[(3 * 4 + hcl) * 17 + batt] + bi_o;
      // --- 7. elementwise cell update (c in register) ---
      float ii = 1.f / (1.f + __expf(-gi));
      float ff = 1.f / (1.f + __expf(-gf));
      float gt = 1.f - 2.f / (1.f + __expf(2.f * gg));   // tanh
      float oo = 1.f / (1.f + __expf(-go));
      c = ff * c + ii * gt;
      float hv2 = oo * (1.f - 2.f / (1.f + __expf(2.f * c)));
      // --- 8. h store: pack 2 bf16 -> one sc0 dword store; fire-and-forget ---
      float hn = __shfl_xor(hv2, 1, 64);    // partner shares (batt, hcl^1)
      if ((hcl & 1) == 0) {
        unsigned short ulo = __builtin_bit_cast(unsigned short, __float2bfloat16(hv2));
        unsigned short uhi = __builtin_bit_cast(unsigned short, __float2bfloat16(hn));
        unsigned pk = ((unsigned)uhi << 16) | (unsigned)ulo;
        size_t uidx = (((size_t)(dir * (S_ + 1) + s + 1) * B_ + b) * H_ + hg) >> 1;
        if (fastu) {
          // expcnt(0) inside the asm: VMEM stores read their data VGPR
          // asynchronously; without it the compiler may reuse pk's register
          // before the store consumes it (round-0 hang mechanism).
          asm volatile("global_store_dword %0, %1, off sc0\n\t"
                       "s_waitcnt expcnt(0)"
                       :: "v"(hh_u + uidx), "v"(pk) : "memory");
        } else {
          __hip_atomic_store(hh_u + uidx, pk, __ATOMIC_RELAXED,
                             __HIP_MEMORY_SCOPE_AGENT);
        }
      }
    }
    // --- 9. write prefetched x(s+1) into pool x-region (loads long landed) ---
    if (xok) {
      int i0 = tid, i1 = tid + 256, i2 = tid + 512;
      *(u32x4_t*)(pool + (i0 / 40) * ASTR + (i0 % 40) * 8) = xpf0;
      *(u32x4_t*)(pool + (i1 / 40) * ASTR + (i1 % 40) * 8) = xpf1;
      if (i2 < 640)
        *(u32x4_t*)(pool + (i2 / 40) * ASTR + (i2 % 40) * 8) = xpf2;
    }
    BAR_LDS();   // B3: x(s+1) staged; also fences pool-h reads (step 5) of
                 // ALL waves before next iteration's h staging (step 4)
  }
}

// ---------------------------------------------------------------------------
// feats[(b*S+s)*T + t] = [hf(s) | hb(s)] . W_out[t,:] + b_out[t]. block per s.
// Output layout [b][s][t] so the CRF scan reads contiguously per batch.
// LDS tile stride padded 1024->1032 to break the 4-way t-lane bank conflict.
__launch_bounds__(256)
__global__ void feats_kernel(const float* __restrict__ Wout,
                             const float* __restrict__ bout,
                             char* __restrict__ ws) {
  __shared__ float wl[12 * 1032];   // 49,536 B
  const int s = blockIdx.x, tid = threadIdx.x;
  for (int i = tid; i < 12 * 1024 / 4; i += 256) {
    int idx4 = i * 4;
    int t = idx4 >> 10, k = idx4 & 1023;
    *(float4*)(wl + t * 1032 + k) = *(const float4*)(Wout + idx4);
  }
  __syncthreads();
  const __hip_bfloat16* hh = (const __hip_bfloat16*)(ws + HH_OFF);
  float* fe = (float*)(ws + FE_OFF);
  int b = tid >> 2, tg = tid & 3, t0 = tg * 3;
  const __hip_bfloat16* hf = hh + (size_t)(0 * (S_ + 1) + s + 1) * B_ * H_ + (size_t)b * H_;
  const __hip_bfloat16* hb = hh + (size_t)(1 * (S_ + 1) + (S_ - s)) * B_ * H_ + (size_t)b * H_;
  float a0 = 0.f, a1 = 0.f, a2 = 0.f;
  for (int half = 0; half < 2; half++) {
    const __hip_bfloat16* hp = half ? hb : hf;
    int wof = half * 512;
    for (int k = 0; k < 512; k += 8) {
      uint4 raw = *(const uint4*)(hp + k);
      const __hip_bfloat16* hv = (const __hip_bfloat16*)&raw;
      float hfl[8];
      #pragma unroll
      for (int j = 0; j < 8; j++) hfl[j] = __bfloat162float(hv[j]);
      #pragma unroll
      for (int j = 0; j < 8; j++) {
        a0 += hfl[j] * wl[(t0 + 0) * 1032 + wof + k + j];
        a1 += hfl[j] * wl[(t0 + 1) * 1032 + wof + k + j];
        a2 += hfl[j] * wl[(t0 + 2) * 1032 + wof + k + j];
      }
    }
  }
  float* o = fe + ((size_t)b * S_ + s) * T_;
  o[t0 + 0] = a0 + bout[t0 + 0];
  o[t0 + 1] = a1 + bout[t0 + 1];
  o[t0 + 2] = a2 + bout[t0 + 2];
}

// ---------------------------------------------------------------------------
// CRF forward scan: one wave per batch element; lane = next-tag (<12).
// Software-pipelined: load feat(s+1) while computing step s.
__launch_bounds__(64)
__global__ void crf_kernel(const int* __restrict__ lengths,
                           const float* __restrict__ trans,
                           char* __restrict__ ws) {
  const int b = blockIdx.x, lane = threadIdx.x;
  const float* fe = (const float*)(ws + FE_OFF);
  float* lse = (float*)(ws + LSE_OFF);
  const float* fb = fe + (size_t)b * S_ * T_;
  float tr[12];
  #pragma unroll
  for (int p = 0; p < 12; p++) tr[p] = (lane < 12) ? trans[lane * 12 + p] : 0.f;
  float tstop = (lane < 12) ? trans[11 * 12 + lane] : 0.f;  // STOP row
  float alpha = (lane == 10) ? 0.f : NEGV;                  // START tag
  const int len = lengths[b];
  float feat = (lane < 12) ? fb[lane] : 0.f;
  for (int s = 0; s < S_; s++) {
    float fn = (lane < 12 && s + 1 < S_) ? fb[(size_t)(s + 1) * T_ + lane] : 0.f;
    float av[12];
    #pragma unroll
    for (int p = 0; p < 12; p++) av[p] = __shfl(alpha, p, 64) + tr[p];
    float mx = av[0];
    #pragma unroll
    for (int p = 1; p < 12; p++) mx = fmaxf(mx, av[p]);
    float sum = 0.f;
    #pragma unroll
    for (int p = 0; p < 12; p++) sum += __expf(av[p] - mx);
    float nw = mx + __logf(sum) + feat;
    if (s < len && lane < 12) alpha = nw;
    feat = fn;
  }
  float tv = (lane < 12) ? (alpha + tstop) : -3.0e38f;
  float mx = tv;
  #pragma unroll
  for (int off = 32; off > 0; off >>= 1) mx = fmaxf(mx, __shfl_xor(mx, off, 64));
  float sum = __expf(tv - mx);
  #pragma unroll
  for (int off = 32; off > 0; off >>= 1) sum += __shfl_xor(sum, off, 64);
  if (lane == 0) lse[b] = mx + __logf(sum);
}

__global__ void final_kernel(char* __restrict__ ws, float* __restrict__ out) {
  const float* lse = (const float*)(ws + LSE_OFF);
  float v = lse[threadIdx.x];
  #pragma unroll
  for (int off = 32; off > 0; off >>= 1) v += __shfl_xor(v, off, 64);
  if (threadIdx.x == 0) out[0] = v * (1.f / 64.f);
}

// ---------------------------------------------------------------------------
extern "C" void kernel_launch(void* const* d_in, const int* in_sizes, int n_in,
                              void* d_out, int out_size, void* d_ws, size_t ws_size,
                              hipStream_t stream) {
  (void)in_sizes; (void)n_in; (void)out_size; (void)ws_size;
  const int* tokens = (const int*)d_in[0];
  const int* lengths = (const int*)d_in[1];
  const float* Wemb = (const float*)d_in[2];
  const float* Wih_f = (const float*)d_in[3];
  const float* Whh_f = (const float*)d_in[4];
  const float* b_f = (const float*)d_in[5];
  const float* Wih_b = (const float*)d_in[6];
  const float* Whh_b = (const float*)d_in[7];
  const float* b_b = (const float*)d_in[8];
  const float* h0 = (const float*)d_in[9];
  const float* c0 = (const float*)d_in[10];
  const float* Wout = (const float*)d_in[11];
  const float* bout = (const float*)d_in[12];
  const float* trans = (const float*)d_in[13];
  char* ws = (char*)d_ws;
  float* out = (float*)d_out;

  int prep_items = 2 * NT16 * KC_TOT * 64 + 2 * B_ * H_ + S_ * B_ * (KPADX / 8)
                 + 2 * (S_ * B_ * H_ * 2) / 16 + 256;
  hipLaunchKernelGGL(prep_kernel, dim3((prep_items + 255) / 256), dim3(256), 0, stream,
                     Wih_f, Whh_f, Wih_b, Whh_b, h0, tokens, Wemb, ws);
  hipLaunchKernelGGL(lstm_persist, dim3(256), dim3(256), 0, stream, b_f, b_b, c0, ws);
  hipLaunchKernelGGL(feats_kernel, dim3(S_), dim3(256), 0, stream, Wout, bout, ws);
  hipLaunchKernelGGL(crf_kernel, dim3(B_), dim3(64), 0, stream, lengths, trans, ws);
  hipLaunchKernelGGL(final_kernel, dim3(1), dim3(64), 0, stream, ws, out);
}

// Round 9
// 1235.822 us; speedup vs baseline: 16.9002x; 1.0718x over previous
//
#include <hip/hip_runtime.h>
#include <hip/hip_bf16.h>

// ---------------------------------------------------------------------------
// BiLSTM (persistent bf16-MFMA kernel, register-resident weights + cell state,
// BARRIER-FREE data-flow sync: consumers poll sentinel-initialized h slots;
// producers fire-and-forget stores) + CRF forward.
// Base = round-8 (941us: round-4 protocol + wave-private gate transpose, no
// B2 barrier). ONE change this revision: poll ROUND 0 is software-pipelined
// under the x-MFMA phase — the 4 sc0 loads are ISSUED before the x-MFMAs and
// waited (vmcnt(0)) after them, so the ~300cy L2 latency of the first poll
// round hides under compute instead of sitting on the 512-step serial chain.
// sched_barrier(0) after both asm blocks per methodology rule #18 (compiler
// otherwise hoists the register-only sentinel checks past the inline-asm
// waitcnt). Retry loop stays fused/bounded with wdog + agent fallback.
constexpr int B_ = 64, S_ = 512, E_ = 300, H_ = 512, T_ = 12;
constexpr int G4 = 4 * H_;          // 2048 gate rows
constexpr int KPADX = 320;          // E padded to 320 (zeros 300..319)
constexpr int KTOT = KPADX + H_;    // 832 total K (x | h)
constexpr int KC_TOT = KTOT / 32;   // 26 MFMA k-chunks
constexpr int KC_X = KPADX / 32;    // 10 x-only chunks (h-independent)
constexpr int NT16 = G4 / 16;       // 128 16-wide n tiles
constexpr float NEGV = -10000.0f;
constexpr int ASTR = 840;           // LDS A-row stride in shorts (832 + 8)
constexpr unsigned SENT = 0xFFFFFFFFu;  // sentinel dword (bf16 pair = -NaN,-NaN)
constexpr int GLW = 16 * 17;        // per-wave gate-transpose region (floats)

typedef __attribute__((ext_vector_type(8))) short bf16x8_t;
typedef __attribute__((ext_vector_type(4))) float f32x4_t;
typedef __attribute__((ext_vector_type(4))) unsigned u32x4_t;

// ---- workspace layout (bytes) ---------------------------------------------
constexpr size_t WC_OFF = 0;
constexpr size_t WC_BYTES = (size_t)2 * NT16 * KC_TOT * 64 * 8 * 2;  // 6,815,744
constexpr size_t XC_OFF = WC_OFF + WC_BYTES;
constexpr size_t XC_BYTES = (size_t)S_ * B_ * KPADX * 2;             // 20,971,520
constexpr size_t HH_OFF = XC_OFF + XC_BYTES;
constexpr size_t HH_BYTES = (size_t)2 * (S_ + 1) * B_ * H_ * 2;      // 67,239,936
constexpr size_t FE_OFF = HH_OFF + HH_BYTES;
constexpr size_t FE_BYTES = (size_t)S_ * B_ * T_ * 4;                // 1,572,864
constexpr size_t LSE_OFF = FE_OFF + FE_BYTES;
// CHK: 256 u32 placement-check slots INSIDE the FE region (feats_kernel runs
// after lstm_persist and fully rewrites FE, so this costs no workspace).
constexpr size_t CHK_OFF = FE_OFF;

// raw barrier: order LDS only; leave global loads in flight (no vmcnt drain).
#define BAR_LDS() do {                                         \
    asm volatile("s_waitcnt lgkmcnt(0)" ::: "memory");         \
    __builtin_amdgcn_s_barrier();                              \
    __builtin_amdgcn_sched_barrier(0);                         \
  } while (0)

// ---------------------------------------------------------------------------
// prep: (1) weights -> bf16 MFMA B-fragment order (4 gates x 4 hcols per
// tile); (2) h0 -> bf16 h_hist slot 0; (3) embedding gather xc[s][b][320]
// bf16; (4) sentinel-fill hh slots 1..S; (5) sentinel-fill the 256-entry XCC
// placement-check array (in FE region).
__global__ void prep_kernel(const float* __restrict__ Wih_f, const float* __restrict__ Whh_f,
                            const float* __restrict__ Wih_b, const float* __restrict__ Whh_b,
                            const float* __restrict__ h0,
                            const int* __restrict__ tokens, const float* __restrict__ Wemb,
                            char* __restrict__ ws) {
  __hip_bfloat16* wc = (__hip_bfloat16*)(ws + WC_OFF);
  __hip_bfloat16* xc = (__hip_bfloat16*)(ws + XC_OFF);
  __hip_bfloat16* hh = (__hip_bfloat16*)(ws + HH_OFF);
  const int WCN = 2 * NT16 * KC_TOT * 64;   // 425,984
  const int H0N = 2 * B_ * H_;              // 65,536
  const int XCN = S_ * B_ * (KPADX / 8);    // 1,310,720
  const int SFD = (S_ * B_ * H_ * 2) / 16;  // 2,097,152 uint4 per dir
  int idx = blockIdx.x * 256 + threadIdx.x;
  if (idx < WCN) {
    int lane = idx & 63;
    int r = idx >> 6;
    int kc = r % KC_TOT; r /= KC_TOT;
    int tt = r % NT16;
    int dir = r / NT16;
    int n16 = lane & 15, quad = lane >> 4;
    int nt = tt >> 2, wvq = tt & 3;
    // column c = n16 = gate*4 + hcl  ->  original gate row:
    int j = (n16 >> 2) * H_ + nt * 16 + wvq * 4 + (n16 & 3);
    int k0 = kc * 32 + quad * 8;
    const float* Wih = dir ? Wih_b : Wih_f;
    const float* Whh = dir ? Whh_b : Whh_f;
    __hip_bfloat16* dst = wc + (size_t)idx * 8;
    #pragma unroll
    for (int jj = 0; jj < 8; jj++) {
      int k = k0 + jj;
      float f;
      if (k < E_) f = Wih[(size_t)j * E_ + k];
      else if (k < KPADX) f = 0.f;
      else f = Whh[(size_t)j * H_ + (k - KPADX)];
      dst[jj] = __float2bfloat16(f);
    }
  } else if (idx < WCN + H0N) {
    int i = idx - WCN;                       // dir*B*H + b*H + h
    int dir = i / (B_ * H_), rem = i % (B_ * H_);
    hh[(size_t)dir * (S_ + 1) * B_ * H_ + rem] = __float2bfloat16(h0[i]);
  } else if (idx < WCN + H0N + XCN) {
    int i = idx - WCN - H0N;                 // sb*40 + c8
    int c8 = i % 40, sb = i / 40;            // sb = s*B + b
    int s = sb >> 6, b = sb & 63;
    int k0 = c8 * 8;
    const float* src = Wemb + (size_t)tokens[(size_t)b * S_ + s] * E_;
    __hip_bfloat16 v[8];
    if (k0 + 8 <= E_) {
      float4 f0 = *(const float4*)(src + k0);
      float4 f1 = *(const float4*)(src + k0 + 4);
      v[0] = __float2bfloat16(f0.x); v[1] = __float2bfloat16(f0.y);
      v[2] = __float2bfloat16(f0.z); v[3] = __float2bfloat16(f0.w);
      v[4] = __float2bfloat16(f1.x); v[5] = __float2bfloat16(f1.y);
      v[6] = __float2bfloat16(f1.z); v[7] = __float2bfloat16(f1.w);
    } else {
      #pragma unroll
      for (int jj = 0; jj < 8; jj++) {
        int k = k0 + jj;
        v[jj] = __float2bfloat16(k < E_ ? src[k] : 0.f);
      }
    }
    *(uint4*)(xc + (size_t)sb * KPADX + k0) = *(const uint4*)v;
  } else if (idx < WCN + H0N + XCN + 2 * SFD) {
    int i = idx - WCN - H0N - XCN;
    int dir = i / SFD, j = i % SFD;
    // sentinel-fill hh[dir][1..S][*][*]
    uint4* dst = (uint4*)(hh + (size_t)dir * (S_ + 1) * B_ * H_ + B_ * H_);
    uint4 sv; sv.x = SENT; sv.y = SENT; sv.z = SENT; sv.w = SENT;
    dst[j] = sv;
  } else if (idx < WCN + H0N + XCN + 2 * SFD + 256) {
    ((unsigned*)(ws + CHK_OFF))[idx - (WCN + H0N + XCN + 2 * SFD)] = SENT;
  }
}

// ---------------------------------------------------------------------------
// Persistent BiLSTM. grid = 256 = group(8 = dir x mt, == bid&7 -> XCD) x
// nt(32 = bid>>3). block = 256. Weights in registers; cell state in a
// register. Consumers poll h(s) 16B chunks (sentinel-initialized, sc0 =
// XCD-local L2); producers fire-and-forget sc0 dword stores. Wave wv owns
// output tile = 4 gates x 4 hcols -> gate transpose is wave-private.
__launch_bounds__(256, 1)
__global__ void lstm_persist(const float* __restrict__ bias_f,
                             const float* __restrict__ bias_b,
                             const float* __restrict__ c0,
                             char* __restrict__ ws) {
  __shared__ short pool[16 * ASTR];      // 26,880 B A-tile
  __shared__ float gl[4 * GLW];          // 4,352 B per-wave gate transpose
  const int bid = blockIdx.x;
  // --- XCD-local remap: group g = bid&7 (round-robin -> one XCD per group) ---
  const int g = bid & 7, nt = bid >> 3, dir = g >> 2, mt = g & 3;
  const int tid = threadIdx.x, lane = tid & 63, wv = tid >> 6;
  const int quad = lane >> 4, l16 = lane & 15;
  const __hip_bfloat16* wc = (const __hip_bfloat16*)(ws + WC_OFF);
  const __hip_bfloat16* xc = (const __hip_bfloat16*)(ws + XC_OFF);
  const __hip_bfloat16* hhb = (const __hip_bfloat16*)(ws + HH_OFF);
  unsigned* hh_u = (unsigned*)(ws + HH_OFF);

  // --- load B fragments into registers, once ---
  bf16x8_t bfr[KC_TOT];
  #pragma unroll
  for (int kc = 0; kc < KC_TOT; kc++) {
    size_t boff = (((size_t)dir * NT16 + (nt * 4 + wv)) * KC_TOT + kc) * 64 + lane;
    bfr[kc] = *(const bf16x8_t*)(wc + boff * 8);
  }
  // --- per-thread cell-update assignment: (batch batt, hcol hg) ---
  const int batt = quad * 4 + (l16 >> 2), hcl = l16 & 3;
  const int b = mt * 16 + batt, hg = nt * 16 + wv * 4 + hcl;
  float c = c0[(size_t)(dir * B_ + b) * H_ + hg];
  const float* bias = dir ? bias_b : bias_f;
  const float bi_i = bias[0 * H_ + hg], bi_f = bias[1 * H_ + hg];
  const float bi_g = bias[2 * H_ + hg], bi_o = bias[3 * H_ + hg];

  // --- placement check: publish XCC id, poll all 256, decide uniformly ------
  int fastu;
  {
    unsigned* chk = (unsigned*)(ws + CHK_OFF);
    unsigned* chkl = (unsigned*)pool;          // reuse LDS as scratch
    if (tid == 0) {
      unsigned xcc;
      asm volatile("s_getreg_b32 %0, hwreg(HW_REG_XCC_ID)" : "=s"(xcc));
      __hip_atomic_store(chk + bid, xcc & 0xFu, __ATOMIC_RELAXED,
                         __HIP_MEMORY_SCOPE_AGENT);
    }
    unsigned myv;
    for (;;) {
      myv = __hip_atomic_load(chk + tid, __ATOMIC_RELAXED, __HIP_MEMORY_SCOPE_AGENT);
      if (myv != SENT) break;
      __builtin_amdgcn_s_sleep(4);
    }
    chkl[tid] = myv;
    __syncthreads();
    bool f = true;
    unsigned mask = 0;
    for (int gg = 0; gg < 8; gg++) {
      unsigned v0 = chkl[gg];
      f = f && (v0 < 32u);
      mask |= (1u << (v0 & 31u));
      for (int m = 1; m < 32; m++) f = f && (chkl[gg + 8 * m] == v0);
    }
    f = f && (__popc(mask) == 8);   // 8 groups on 8 DISTINCT XCDs (garbage guard)
    fastu = __builtin_amdgcn_readfirstlane(f ? 1 : 0);
    __syncthreads();                // before pool reuse below
  }

  // --- pre-stage x(0) into pool x-region ---
  {
    int spos0 = dir ? (S_ - 1) : 0;
    for (int i = tid; i < 16 * 40; i += 256) {
      int row = i / 40, c8 = i % 40;
      *(uint4*)(pool + row * ASTR + c8 * 8) =
          *(const uint4*)(xc + ((size_t)spos0 * B_ + mt * 16 + row) * KPADX + c8 * 8);
    }
  }
  __syncthreads();   // x(0) visible before first x-MFMA phase

  // poll/stage map: 16KB h tile = 1024 16B chunks; thread owns chunks
  // tid + k*256 (k=0..3): row = i>>6, col16 = i&63.
  int wdog = 0;   // latches 1 if the sc0 poll ever exhausts its budget
  for (int s = 0; s < S_; s++) {
    // --- 1a. ISSUE poll round 0 (no wait) — latency hides under x-MFMAs ---
    const u32x4_t* pbase = (const u32x4_t*)(hhb +
        ((size_t)(dir * (S_ + 1) + s) * B_ + mt * 16) * H_);
    const u32x4_t* q0 = pbase + tid;
    const u32x4_t* q1 = pbase + tid + 256;
    const u32x4_t* q2 = pbase + tid + 512;
    const u32x4_t* q3 = pbase + tid + 768;
    u32x4_t t0, t1, t2, t3;
    const bool try0 = fastu && !wdog;
    if (try0) {
      asm volatile(
          "global_load_dwordx4 %0, %4, off sc0\n\t"
          "global_load_dwordx4 %1, %5, off sc0\n\t"
          "global_load_dwordx4 %2, %6, off sc0\n\t"
          "global_load_dwordx4 %3, %7, off sc0"
          : "=&v"(t0), "=&v"(t1), "=&v"(t2), "=&v"(t3)
          : "v"(q0), "v"(q1), "v"(q2), "v"(q3)
          : "memory");
      __builtin_amdgcn_sched_barrier(0);
    }
    // --- 1b. x-part MFMAs (h-independent; overlap poll round 0) ---
    f32x4_t acc = (f32x4_t)(0.f);
    #pragma unroll
    for (int kc = 0; kc < KC_X; kc++) {
      bf16x8_t af = *(const bf16x8_t*)(pool + l16 * ASTR + kc * 32 + quad * 8);
      acc = __builtin_amdgcn_mfma_f32_16x16x32_bf16(af, bfr[kc], acc, 0, 0, 0);
    }
    // --- 2. wait round 0, check; fused retry rounds if needed ---
    bool got = false;
    if (try0) {
      asm volatile("s_waitcnt vmcnt(0)" ::: "memory");
      __builtin_amdgcn_sched_barrier(0);
      bool ok = t0[0] != SENT && t0[1] != SENT && t0[2] != SENT && t0[3] != SENT &&
                t1[0] != SENT && t1[1] != SENT && t1[2] != SENT && t1[3] != SENT &&
                t2[0] != SENT && t2[1] != SENT && t2[2] != SENT && t2[3] != SENT &&
                t3[0] != SENT && t3[1] != SENT && t3[2] != SENT && t3[3] != SENT;
      for (int tries = 0; tries < 16384 && !ok; ++tries) {
        __builtin_amdgcn_s_sleep(1);
        asm volatile(
            "global_load_dwordx4 %0, %4, off sc0\n\t"
            "global_load_dwordx4 %1, %5, off sc0\n\t"
            "global_load_dwordx4 %2, %6, off sc0\n\t"
            "global_load_dwordx4 %3, %7, off sc0\n\t"
            "s_waitcnt vmcnt(0)"
            : "=&v"(t0), "=&v"(t1), "=&v"(t2), "=&v"(t3)
            : "v"(q0), "v"(q1), "v"(q2), "v"(q3)
            : "memory");
        __builtin_amdgcn_sched_barrier(0);
        ok = t0[0] != SENT && t0[1] != SENT && t0[2] != SENT && t0[3] != SENT &&
             t1[0] != SENT && t1[1] != SENT && t1[2] != SENT && t1[3] != SENT &&
             t2[0] != SENT && t2[1] != SENT && t2[2] != SENT && t2[3] != SENT &&
             t3[0] != SENT && t3[1] != SENT && t3[2] != SENT && t3[3] != SENT;
      }
      got = ok;
      if (!got) wdog = 1;   // permanent per-thread fallback
    }
    if (!got) {
      // agent-scope sentinel poll (device-coherent, unconditionally safe)
      const unsigned long long* qq = (const unsigned long long*)pbase;
      u32x4_t tt[4];
      bool ok = false;
      while (!ok) {
        ok = true;
        #pragma unroll
        for (int k = 0; k < 4; k++) {
          int i = tid + k * 256;
          unsigned long long a0 = __hip_atomic_load(qq + 2 * i, __ATOMIC_RELAXED,
                                                    __HIP_MEMORY_SCOPE_AGENT);
          unsigned long long a1 = __hip_atomic_load(qq + 2 * i + 1, __ATOMIC_RELAXED,
                                                    __HIP_MEMORY_SCOPE_AGENT);
          tt[k][0] = (unsigned)a0; tt[k][1] = (unsigned)(a0 >> 32);
          tt[k][2] = (unsigned)a1; tt[k][3] = (unsigned)(a1 >> 32);
          ok = ok && tt[k][0] != SENT && tt[k][1] != SENT &&
                     tt[k][2] != SENT && tt[k][3] != SENT;
        }
        if (!ok) __builtin_amdgcn_s_sleep(1);
      }
      t0 = tt[0]; t1 = tt[1]; t2 = tt[2]; t3 = tt[3];
    }
    // --- 3. issue x(s+1) prefetch loads into VGPRs (consumed at step 9) ---
    u32x4_t xpf0, xpf1, xpf2;
    const bool xok = (s + 1 < S_);
    if (xok) {
      int sposn = dir ? (S_ - 2 - s) : (s + 1);
      const u32x4_t* xq = (const u32x4_t*)xc;   // 8 bf16 per u32x4
      int i0 = tid, i1 = tid + 256, i2 = tid + 512;
      xpf0 = xq[((size_t)sposn * B_ + mt * 16 + i0 / 40) * 40 + i0 % 40];
      xpf1 = xq[((size_t)sposn * B_ + mt * 16 + i1 / 40) * 40 + i1 % 40];
      if (i2 < 640)
        xpf2 = xq[((size_t)sposn * B_ + mt * 16 + i2 / 40) * 40 + i2 % 40];
    }
    // --- 4. stage h(s) -> LDS h-region (4 x b128) ---
    {
      int r0 = tid >> 6, c0v = tid & 63;
      *(u32x4_t*)(pool + r0 * ASTR + KPADX + c0v * 8) = t0;
      int i1 = tid + 256; int r1 = i1 >> 6, c1v = i1 & 63;
      *(u32x4_t*)(pool + r1 * ASTR + KPADX + c1v * 8) = t1;
      int i2 = tid + 512; int r2 = i2 >> 6, c2v = i2 & 63;
      *(u32x4_t*)(pool + r2 * ASTR + KPADX + c2v * 8) = t2;
      int i3 = tid + 768; int r3 = i3 >> 6, c3v = i3 & 63;
      *(u32x4_t*)(pool + r3 * ASTR + KPADX + c3v * 8) = t3;
    }
    BAR_LDS();   // B1: h tile staged (LDS-only wait; xpf loads stay in flight)
    // --- 5. h-part MFMAs (same accumulation order: kc 10..25) ---
    #pragma unroll
    for (int kc = KC_X; kc < KC_TOT; kc++) {
      bf16x8_t af = *(const bf16x8_t*)(pool + l16 * ASTR + kc * 32 + quad * 8);
      acc = __builtin_amdgcn_mfma_f32_16x16x32_bf16(af, bfr[kc], acc, 0, 0, 0);
    }
    // --- 6. WAVE-PRIVATE gate transpose (no barrier): write col-major,
    //        lgkmcnt, read back 4 gates for this thread's (batt, hcl). ---
    {
      float* glw = gl + wv * GLW;
      #pragma unroll
      for (int r = 0; r < 4; r++)
        glw[l16 * 17 + quad * 4 + r] = acc[r];
      asm volatile("s_waitcnt lgkmcnt(0)" ::: "memory");
      __builtin_amdgcn_sched_barrier(0);
      float gi = glw[(0 * 4 + hcl) * 17 + batt] + bi_i;
      float gf = glw[(1 * 4 + hcl) * 17 + batt] + bi_f;
      float gg = glw[(2 * 4 + hcl) * 17 + batt] + bi_g;
      float go = glw[(3 * 4 + hcl) * 17 + batt] + bi_o;
      // --- 7. elementwise cell update (c in register) ---
      float ii = 1.f / (1.f + __expf(-gi));
      float ff = 1.f / (1.f + __expf(-gf));
      float gt = 1.f - 2.f / (1.f + __expf(2.f * gg));   // tanh
      float oo = 1.f / (1.f + __expf(-go));
      c = ff * c + ii * gt;
      float hv2 = oo * (1.f - 2.f / (1.f + __expf(2.f * c)));
      // --- 8. h store: pack 2 bf16 -> one sc0 dword store; fire-and-forget ---
      float hn = __shfl_xor(hv2, 1, 64);    // partner shares (batt, hcl^1)
      if ((hcl & 1) == 0) {
        unsigned short ulo = __builtin_bit_cast(unsigned short, __float2bfloat16(hv2));
        unsigned short uhi = __builtin_bit_cast(unsigned short, __float2bfloat16(hn));
        unsigned pk = ((unsigned)uhi << 16) | (unsigned)ulo;
        size_t uidx = (((size_t)(dir * (S_ + 1) + s + 1) * B_ + b) * H_ + hg) >> 1;
        if (fastu) {
          // expcnt(0) inside the asm: VMEM stores read their data VGPR
          // asynchronously; without it the compiler may reuse pk's register
          // before the store consumes it (round-0 hang mechanism).
          asm volatile("global_store_dword %0, %1, off sc0\n\t"
                       "s_waitcnt expcnt(0)"
                       :: "v"(hh_u + uidx), "v"(pk) : "memory");
        } else {
          __hip_atomic_store(hh_u + uidx, pk, __ATOMIC_RELAXED,
                             __HIP_MEMORY_SCOPE_AGENT);
        }
      }
    }
    // --- 9. write prefetched x(s+1) into pool x-region (loads long landed) ---
    if (xok) {
      int i0 = tid, i1 = tid + 256, i2 = tid + 512;
      *(u32x4_t*)(pool + (i0 / 40) * ASTR + (i0 % 40) * 8) = xpf0;
      *(u32x4_t*)(pool + (i1 / 40) * ASTR + (i1 % 40) * 8) = xpf1;
      if (i2 < 640)
        *(u32x4_t*)(pool + (i2 / 40) * ASTR + (i2 % 40) * 8) = xpf2;
    }
    BAR_LDS();   // B3: x(s+1) staged; also fences pool-h reads (step 5) of
                 // ALL waves before next iteration's h staging (step 4)
  }
}

// ---------------------------------------------------------------------------
// feats[(b*S+s)*T + t] = [hf(s) | hb(s)] . W_out[t,:] + b_out[t]. block per s.
// Output layout [b][s][t] so the CRF scan reads contiguously per batch.
// LDS tile stride padded 1024->1032 to break the 4-way t-lane bank conflict.
__launch_bounds__(256)
__global__ void feats_kernel(const float* __restrict__ Wout,
                             const float* __restrict__ bout,
                             char* __restrict__ ws) {
  __shared__ float wl[12 * 1032];   // 49,536 B
  const int s = blockIdx.x, tid = threadIdx.x;
  for (int i = tid; i < 12 * 1024 / 4; i += 256) {
    int idx4 = i * 4;
    int t = idx4 >> 10, k = idx4 & 1023;
    *(float4*)(wl + t * 1032 + k) = *(const float4*)(Wout + idx4);
  }
  __syncthreads();
  const __hip_bfloat16* hh = (const __hip_bfloat16*)(ws + HH_OFF);
  float* fe = (float*)(ws + FE_OFF);
  int b = tid >> 2, tg = tid & 3, t0 = tg * 3;
  const __hip_bfloat16* hf = hh + (size_t)(0 * (S_ + 1) + s + 1) * B_ * H_ + (size_t)b * H_;
  const __hip_bfloat16* hb = hh + (size_t)(1 * (S_ + 1) + (S_ - s)) * B_ * H_ + (size_t)b * H_;
  float a0 = 0.f, a1 = 0.f, a2 = 0.f;
  for (int half = 0; half < 2; half++) {
    const __hip_bfloat16* hp = half ? hb : hf;
    int wof = half * 512;
    for (int k = 0; k < 512; k += 8) {
      uint4 raw = *(const uint4*)(hp + k);
      const __hip_bfloat16* hv = (const __hip_bfloat16*)&raw;
      float hfl[8];
      #pragma unroll
      for (int j = 0; j < 8; j++) hfl[j] = __bfloat162float(hv[j]);
      #pragma unroll
      for (int j = 0; j < 8; j++) {
        a0 += hfl[j] * wl[(t0 + 0) * 1032 + wof + k + j];
        a1 += hfl[j] * wl[(t0 + 1) * 1032 + wof + k + j];
        a2 += hfl[j] * wl[(t0 + 2) * 1032 + wof + k + j];
      }
    }
  }
  float* o = fe + ((size_t)b * S_ + s) * T_;
  o[t0 + 0] = a0 + bout[t0 + 0];
  o[t0 + 1] = a1 + bout[t0 + 1];
  o[t0 + 2] = a2 + bout[t0 + 2];
}

// ---------------------------------------------------------------------------
// CRF forward scan: one wave per batch element; lane = next-tag (<12).
// Software-pipelined: load feat(s+1) while computing step s.
__launch_bounds__(64)
__global__ void crf_kernel(const int* __restrict__ lengths,
                           const float* __restrict__ trans,
                           char* __restrict__ ws) {
  const int b = blockIdx.x, lane = threadIdx.x;
  const float* fe = (const float*)(ws + FE_OFF);
  float* lse = (float*)(ws + LSE_OFF);
  const float* fb = fe + (size_t)b * S_ * T_;
  float tr[12];
  #pragma unroll
  for (int p = 0; p < 12; p++) tr[p] = (lane < 12) ? trans[lane * 12 + p] : 0.f;
  float tstop = (lane < 12) ? trans[11 * 12 + lane] : 0.f;  // STOP row
  float alpha = (lane == 10) ? 0.f : NEGV;                  // START tag
  const int len = lengths[b];
  float feat = (lane < 12) ? fb[lane] : 0.f;
  for (int s = 0; s < S_; s++) {
    float fn = (lane < 12 && s + 1 < S_) ? fb[(size_t)(s + 1) * T_ + lane] : 0.f;
    float av[12];
    #pragma unroll
    for (int p = 0; p < 12; p++) av[p] = __shfl(alpha, p, 64) + tr[p];
    float mx = av[0];
    #pragma unroll
    for (int p = 1; p < 12; p++) mx = fmaxf(mx, av[p]);
    float sum = 0.f;
    #pragma unroll
    for (int p = 0; p < 12; p++) sum += __expf(av[p] - mx);
    float nw = mx + __logf(sum) + feat;
    if (s < len && lane < 12) alpha = nw;
    feat = fn;
  }
  float tv = (lane < 12) ? (alpha + tstop) : -3.0e38f;
  float mx = tv;
  #pragma unroll
  for (int off = 32; off > 0; off >>= 1) mx = fmaxf(mx, __shfl_xor(mx, off, 64));
  float sum = __expf(tv - mx);
  #pragma unroll
  for (int off = 32; off > 0; off >>= 1) sum += __shfl_xor(sum, off, 64);
  if (lane == 0) lse[b] = mx + __logf(sum);
}

__global__ void final_kernel(char* __restrict__ ws, float* __restrict__ out) {
  const float* lse = (const float*)(ws + LSE_OFF);
  float v = lse[threadIdx.x];
  #pragma unroll
  for (int off = 32; off > 0; off >>= 1) v += __shfl_xor(v, off, 64);
  if (threadIdx.x == 0) out[0] = v * (1.f / 64.f);
}

// ---------------------------------------------------------------------------
extern "C" void kernel_launch(void* const* d_in, const int* in_sizes, int n_in,
                              void* d_out, int out_size, void* d_ws, size_t ws_size,
                              hipStream_t stream) {
  (void)in_sizes; (void)n_in; (void)out_size; (void)ws_size;
  const int* tokens = (const int*)d_in[0];
  const int* lengths = (const int*)d_in[1];
  const float* Wemb = (const float*)d_in[2];
  const float* Wih_f = (const float*)d_in[3];
  const float* Whh_f = (const float*)d_in[4];
  const float* b_f = (const float*)d_in[5];
  const float* Wih_b = (const float*)d_in[6];
  const float* Whh_b = (const float*)d_in[7];
  const float* b_b = (const float*)d_in[8];
  const float* h0 = (const float*)d_in[9];
  const float* c0 = (const float*)d_in[10];
  const float* Wout = (const float*)d_in[11];
  const float* bout = (const float*)d_in[12];
  const float* trans = (const float*)d_in[13];
  char* ws = (char*)d_ws;
  float* out = (float*)d_out;

  int prep_items = 2 * NT16 * KC_TOT * 64 + 2 * B_ * H_ + S_ * B_ * (KPADX / 8)
                 + 2 * (S_ * B_ * H_ * 2) / 16 + 256;
  hipLaunchKernelGGL(prep_kernel, dim3((prep_items + 255) / 256), dim3(256), 0, stream,
                     Wih_f, Whh_f, Wih_b, Whh_b, h0, tokens, Wemb, ws);
  hipLaunchKernelGGL(lstm_persist, dim3(256), dim3(256), 0, stream, b_f, b_b, c0, ws);
  hipLaunchKernelGGL(feats_kernel, dim3(S_), dim3(256), 0, stream, Wout, bout, ws);
  hipLaunchKernelGGL(crf_kernel, dim3(B_), dim3(64), 0, stream, lengths, trans, ws);
  hipLaunchKernelGGL(final_kernel, dim3(1), dim3(64), 0, stream, ws, out);
}